// Round 13
// baseline (1756.096 us; speedup 1.0000x reference)
//
#include <hip/hip_runtime.h>
#include <hip/hip_bf16.h>
#include <math.h>

#define BQ 2
#define SEQ 2048
#define NDIM 1024
#define HEADS 16
#define DH 64
#define NSTEPS 8
#define SCALE 22.60530911f      /* sqrt(511) */
#define SCALE_HEAD 5.567764363f /* sqrt(31)  */
#define INV_SCALE2 (1.0f/511.0f)
#define EXS 8.0325527f          /* SCALE_HEAD * log2(e) */

typedef unsigned short u16;
typedef unsigned char u8;
typedef long long i64;
typedef __attribute__((ext_vector_type(8))) short bf16x8;   // 8 bf16 = 4 VGPR
typedef __attribute__((ext_vector_type(4))) float floatx4;  // MFMA 16x16 acc
typedef __attribute__((ext_vector_type(2))) long long i64x2; // 16B = two fp8 K=32 frags

__device__ __forceinline__ float bf2f(u16 u) {
  union { unsigned int i; float f; } v; v.i = ((unsigned int)u) << 16; return v.f;
}
__device__ __forceinline__ u16 f2bf(float f) {
  union { float f; unsigned int i; } v; v.f = f;
  unsigned int x = v.i;
  return (u16)((x + 0x7fffu + ((x >> 16) & 1u)) >> 16);
}
// raw v_exp_f32 via compiler-modeled builtin (inputs bounded here)
#if __has_builtin(__builtin_amdgcn_exp2f)
__device__ __forceinline__ float exp2_raw(float x) { return __builtin_amdgcn_exp2f(x); }
#else
__device__ __forceinline__ float exp2_raw(float x) { return exp2f(x); }
#endif
#if __has_builtin(__builtin_amdgcn_rcpf)
__device__ __forceinline__ float rcp_raw(float x) { return __builtin_amdgcn_rcpf(x); }
#else
__device__ __forceinline__ float rcp_raw(float x) { return 1.0f/x; }
#endif

// tanh-approx GELU: max |diff vs exact| ~5e-4, below bf16 output quantization.
__device__ __forceinline__ float gelu_tanh(float v) {
  float v2 = v*v;
  float u = v * __builtin_fmaf(0.0356774081f, v2, 0.7978845608f);
  float t = exp2_raw(2.8853900817779268f * u);   // e^{2u}, u in [-5.6, 5.6]
  float th = (t - 1.0f) * rcp_raw(t + 1.0f);
  return 0.5f * v * (1.0f + th);
}

// packed fp8 conversion via HW cvt (gfx950 native fp8 = OCP e4m3fn)
__device__ __forceinline__ int pk4_fp8(float a, float b, float c, float d) {
  int p = 0;
  p = __builtin_amdgcn_cvt_pk_fp8_f32(a, b, p, false);
  p = __builtin_amdgcn_cvt_pk_fp8_f32(c, d, p, true);
  return p;
}

// async global->LDS, 16B per lane; LDS dest = wave-uniform base + lane*16
#define GLD16(gp, lp) __builtin_amdgcn_global_load_lds( \
    (__attribute__((address_space(1))) void*)(gp),      \
    (__attribute__((address_space(3))) void*)(lp), 16, 0, 0)

/* ===================== FRAG-TILED OPERAND LAYOUTS =====================
 * A (attn, per bh, 4MB): element e_raw[i][j]:
 *   I=i>>4, kt2=j>>6, hf=(j>>5)&1, Lhi=(j>>3)&3, e=j&7, l15=i&15
 *   addr = ((I*32 + kt2)*64 + Lhi*16 + l15)*16 + hf*8 + e
 * B (m, per bh, 128KB): element m[d][j]:
 *   nt=d>>4, l15=d&15, kt2=j>>6, hf=(j>>5)&1, Lhi=(j>>3)&3, e=j&7
 *   addr = ((nt*32 + kt2)*64 + Lhi*16 + l15)*16 + hf*8 + e
 * Lane L of an MFMA then loads its frag as one dwordx4 at base + L*16. */

// ---------------- dtype probe: flag=1 if input is fp32 ----------------
__global__ void k_flag0(int* flag) { if (threadIdx.x == 0 && blockIdx.x == 0) *flag = 0; }

__global__ __launch_bounds__(256) void k_probe(const u16* __restrict__ x, int* __restrict__ flag) {
  int i = blockIdx.x * 256 + threadIdx.x;
  float v = bf2f(x[i]);
  if (!(fabsf(v) <= 1e4f)) atomicOr(flag, 1);
}

__global__ __launch_bounds__(256) void k_convert(const void* __restrict__ in, u16* __restrict__ outb,
                                                 const int* __restrict__ flag, int n) {
  int i = blockIdx.x * 256 + threadIdx.x;
  if (i >= n) return;
  if (*flag) outb[i] = f2bf(((const float*)in)[i]);
  else       outb[i] = ((const u16*)in)[i];
}

// ---------------- normalize + scale x -> xs (bf16) ----------------
__global__ __launch_bounds__(256) void k_norm_scale(const u16* __restrict__ x, u16* __restrict__ xs) {
  __shared__ float red[256];
  int row = blockIdx.x;
  const u16* xr = x + (size_t)row * NDIM;
  u16* orow = xs + (size_t)row * NDIM;
  int t = threadIdx.x;
  float vals[4]; float s = 0.f;
#pragma unroll
  for (int e = 0; e < 4; e++) { float v = bf2f(xr[t + 256*e]); vals[e] = v; s += v*v; }
  red[t] = s; __syncthreads();
  for (int o = 128; o > 0; o >>= 1) { if (t < o) red[t] += red[t+o]; __syncthreads(); }
  float sc = SCALE / fmaxf(sqrtf(red[0]), 1e-12f);
#pragma unroll
  for (int e = 0; e < 4; e++) orow[t + 256*e] = f2bf(vals[e] * sc);
}

// ---------------- MFMA GEMM (bf16), BK=64 via dual 32-col slabs ----------------
template<int OUT_BF16, int GELU, int ADDSRC>
__global__ __launch_bounds__(256) void k_gemm(const u16* __restrict__ A, const u16* __restrict__ W,
                                              float* __restrict__ Cf, u16* __restrict__ Cb,
                                              const u16* __restrict__ addsrc, int M, int N, int K) {
  __shared__ __align__(16) u16 As[2][128*32];
  __shared__ __align__(16) u16 Bs[2][128*32];
  int t = threadIdx.x;
  int w = t >> 6, L = t & 63;
  int quad = L >> 4, l15 = L & 15;
  int wr = w >> 1, wc = w & 1;
  int bm = blockIdx.x * 128, bn = blockIdx.y * 128;
  int srow = L >> 2, scol = (L & 3) * 8;
  floatx4 acc[4][4];
#pragma unroll
  for (int i = 0; i < 4; i++)
#pragma unroll
    for (int j = 0; j < 4; j++) acc[i][j] = (floatx4){0.f,0.f,0.f,0.f};

  for (int k0 = 0; k0 < K; k0 += 64) {
#pragma unroll
    for (int c = 0; c < 2; c++) {
      int r = c*64 + w*16 + srow;
      const u16* ap = A + (size_t)(bm + r)*K + k0 + scol;
      const u16* wp = W + (size_t)(bn + r)*K + k0 + scol;
      GLD16(ap,      &As[0][(c*64 + w*16)*32]);
      GLD16(ap + 32, &As[1][(c*64 + w*16)*32]);
      GLD16(wp,      &Bs[0][(c*64 + w*16)*32]);
      GLD16(wp + 32, &Bs[1][(c*64 + w*16)*32]);
    }
    __syncthreads();
#pragma unroll
    for (int s = 0; s < 2; s++) {
      bf16x8 af[4], bfr[4];
#pragma unroll
      for (int mt = 0; mt < 4; mt++) af[mt]  = *(const bf16x8*)&As[s][(wr*64 + mt*16 + l15)*32 + quad*8];
#pragma unroll
      for (int nt = 0; nt < 4; nt++) bfr[nt] = *(const bf16x8*)&Bs[s][(wc*64 + nt*16 + l15)*32 + quad*8];
#pragma unroll
      for (int mt = 0; mt < 4; mt++)
#pragma unroll
        for (int nt = 0; nt < 4; nt++)
          acc[mt][nt] = __builtin_amdgcn_mfma_f32_16x16x32_bf16(af[mt], bfr[nt], acc[mt][nt], 0, 0, 0);
    }
    __syncthreads();
  }
#pragma unroll
  for (int mt = 0; mt < 4; mt++)
#pragma unroll
    for (int reg = 0; reg < 4; reg++) {
      int m = bm + wr*64 + mt*16 + quad*4 + reg;
      size_t rowoff = (size_t)m * N;
#pragma unroll
      for (int nt = 0; nt < 4; nt++) {
        int n = bn + wc*64 + nt*16 + l15;
        float v = acc[mt][nt][reg];
        if (GELU) v = gelu_tanh(v);
        if (ADDSRC) v += bf2f(addsrc[rowoff + n]);
        if (OUT_BF16) Cb[rowoff + n] = f2bf(v);
        else Cf[rowoff + n] = v;
      }
    }
}

// ---------------- w2 GEMM fallback: intra-block split-K only (1 block/CU) ----------
__global__ __launch_bounds__(512) void k_gemm_w2(const u16* __restrict__ A, const u16* __restrict__ W,
                                                 float* __restrict__ Cf,
                                                 const u16* __restrict__ addsrc, int M, int N, int K) {
  __shared__ __align__(16) u16 As[2][128*32];
  __shared__ __align__(16) u16 Bs[2][128*32];
  int t = threadIdx.x;
  int g = t >> 8;
  int tg = t & 255;
  int w = tg >> 6;
  int L = t & 63;
  int quad = L >> 4, l15 = L & 15;
  int wr = w >> 1, wc = w & 1;
  int bm = blockIdx.x * 128, bn = blockIdx.y * 128;
  int srow = L >> 2, scol = (L & 3) * 8;
  int kg0 = g * (K >> 1);
  floatx4 acc[4][4];
#pragma unroll
  for (int i = 0; i < 4; i++)
#pragma unroll
    for (int j = 0; j < 4; j++) acc[i][j] = (floatx4){0.f,0.f,0.f,0.f};

  for (int k0 = 0; k0 < (K >> 1); k0 += 32) {
    int kk = kg0 + k0;
#pragma unroll
    for (int c = 0; c < 2; c++) {
      int r = c*64 + w*16 + srow;
      GLD16(A + (size_t)(bm + r)*K + kk + scol, &As[g][(c*64 + w*16)*32]);
      GLD16(W + (size_t)(bn + r)*K + kk + scol, &Bs[g][(c*64 + w*16)*32]);
    }
    __syncthreads();
    bf16x8 af[4], bfr[4];
#pragma unroll
    for (int mt = 0; mt < 4; mt++) af[mt]  = *(const bf16x8*)&As[g][(wr*64 + mt*16 + l15)*32 + quad*8];
#pragma unroll
    for (int nt = 0; nt < 4; nt++) bfr[nt] = *(const bf16x8*)&Bs[g][(wc*64 + nt*16 + l15)*32 + quad*8];
#pragma unroll
    for (int mt = 0; mt < 4; mt++)
#pragma unroll
      for (int nt = 0; nt < 4; nt++)
        acc[mt][nt] = __builtin_amdgcn_mfma_f32_16x16x32_bf16(af[mt], bfr[nt], acc[mt][nt], 0, 0, 0);
    __syncthreads();
  }
  float* LFA = (float*)&As[0][0];
  float* LFB = (float*)&Bs[0][0];
#pragma unroll
  for (int r = 0; r < 2; r++) {
    float* myW = g ? LFA : LFB;
    int mtW = g ? r : (2 + r);
#pragma unroll
    for (int reg = 0; reg < 4; reg++)
#pragma unroll
      for (int nt = 0; nt < 4; nt++)
        myW[(wr*16 + quad*4 + reg)*128 + wc*64 + nt*16 + l15] = acc[mtW][nt][reg];
    __syncthreads();
    float* myR = g ? LFB : LFA;
    int mtS = g ? (2 + r) : r;
#pragma unroll
    for (int reg = 0; reg < 4; reg++) {
      int m = bm + wr*64 + mtS*16 + quad*4 + reg;
      size_t rowoff = (size_t)m * N;
#pragma unroll
      for (int nt = 0; nt < 4; nt++) {
        int n = bn + wc*64 + nt*16 + l15;
        float v = acc[mtS][nt][reg] + myR[(wr*16 + quad*4 + reg)*128 + wc*64 + nt*16 + l15];
        v += bf2f(addsrc[rowoff + n]);
        Cf[rowoff + n] = v;
      }
    }
    __syncthreads();
  }
}

// ---------------- w2 GEMM: inter-block (z=2) + intra-block (g=2) split-K ----------
__global__ __launch_bounds__(512) void k_gemm_w2ks(const u16* __restrict__ A, const u16* __restrict__ W,
                                                   float* __restrict__ pbuf, int M, int N, int K) {
  __shared__ __align__(16) u16 As[2][128*32];
  __shared__ __align__(16) u16 Bs[2][128*32];
  int t = threadIdx.x;
  int g = t >> 8;                 // K-quarter group within block (wave-uniform)
  int tg = t & 255;
  int w = tg >> 6;
  int L = t & 63;
  int quad = L >> 4, l15 = L & 15;
  int wr = w >> 1, wc = w & 1;
  int bm = blockIdx.x * 128, bn = blockIdx.y * 128;
  int z = blockIdx.z;             // K-half
  int srow = L >> 2, scol = (L & 3) * 8;
  int kg0 = z * (K >> 1) + g * (K >> 2);
  floatx4 acc[4][4];
#pragma unroll
  for (int i = 0; i < 4; i++)
#pragma unroll
    for (int j = 0; j < 4; j++) acc[i][j] = (floatx4){0.f,0.f,0.f,0.f};

  for (int k0 = 0; k0 < (K >> 2); k0 += 32) {
    int kk = kg0 + k0;
#pragma unroll
    for (int c = 0; c < 2; c++) {
      int r = c*64 + w*16 + srow;
      GLD16(A + (size_t)(bm + r)*K + kk + scol, &As[g][(c*64 + w*16)*32]);
      GLD16(W + (size_t)(bn + r)*K + kk + scol, &Bs[g][(c*64 + w*16)*32]);
    }
    __syncthreads();
    bf16x8 af[4], bfr[4];
#pragma unroll
    for (int mt = 0; mt < 4; mt++) af[mt]  = *(const bf16x8*)&As[g][(wr*64 + mt*16 + l15)*32 + quad*8];
#pragma unroll
    for (int nt = 0; nt < 4; nt++) bfr[nt] = *(const bf16x8*)&Bs[g][(wc*64 + nt*16 + l15)*32 + quad*8];
#pragma unroll
    for (int mt = 0; mt < 4; mt++)
#pragma unroll
      for (int nt = 0; nt < 4; nt++)
        acc[mt][nt] = __builtin_amdgcn_mfma_f32_16x16x32_bf16(af[mt], bfr[nt], acc[mt][nt], 0, 0, 0);
    __syncthreads();
  }
  float* LFA = (float*)&As[0][0];
  float* LFB = (float*)&Bs[0][0];
  float* pb = pbuf + (size_t)z * M * N;
#pragma unroll
  for (int r = 0; r < 2; r++) {
    float* myW = g ? LFA : LFB;
    int mtW = g ? r : (2 + r);
#pragma unroll
    for (int reg = 0; reg < 4; reg++)
#pragma unroll
      for (int nt = 0; nt < 4; nt++)
        myW[(wr*16 + quad*4 + reg)*128 + wc*64 + nt*16 + l15] = acc[mtW][nt][reg];
    __syncthreads();
    float* myR = g ? LFB : LFA;
    int mtS = g ? (2 + r) : r;
#pragma unroll
    for (int reg = 0; reg < 4; reg++) {
      int m = bm + wr*64 + mtS*16 + quad*4 + reg;
      size_t rowoff = (size_t)m * N;
#pragma unroll
      for (int nt = 0; nt < 4; nt++) {
        int n = bn + wc*64 + nt*16 + l15;
        pb[rowoff + n] = acc[mtS][nt][reg] + myR[(wr*16 + quad*4 + reg)*128 + wc*64 + nt*16 + l15];
      }
    }
    __syncthreads();
  }
}

// reduce: xf = p0 + p1 + bf16(xs); vectorized x4
__global__ __launch_bounds__(256) void k_w2red(const float* __restrict__ p0, const float* __restrict__ p1,
                                               const u16* __restrict__ xs, float* __restrict__ xf, int n) {
  int i = (blockIdx.x * 256 + threadIdx.x) * 4;
  if (i >= n) return;
  float4 a = *(const float4*)(p0 + i);
  float4 b = *(const float4*)(p1 + i);
  ushort4 s = *(const ushort4*)(xs + i);
  float4 o;
  o.x = a.x + b.x + bf2f(s.x);
  o.y = a.y + b.y + bf2f(s.y);
  o.z = a.z + b.z + bf2f(s.z);
  o.w = a.w + b.w + bf2f(s.w);
  *(float4*)(xf + i) = o;
}

// ---------------- per-head normalize q,k -> [B,H,N,DH] bf16 ----------------
__global__ __launch_bounds__(64) void k_headnorm(const u16* __restrict__ qkraw,
                                                 u16* __restrict__ qn, u16* __restrict__ kn) {
  int blk = blockIdx.x;
  int h = blk & (HEADS-1); int bi = blk >> 4;
  int b = bi >> 11, i = bi & (SEQ-1);
  int d = threadIdx.x;
  const u16* base = qkraw + (size_t)bi * (2*NDIM);
  float qv = bf2f(base[h*DH + d]);
  float kv = bf2f(base[NDIM + h*DH + d]);
  float qs = qv*qv, ks = kv*kv;
#pragma unroll
  for (int o = 32; o > 0; o >>= 1) { qs += __shfl_xor(qs, o); ks += __shfl_xor(ks, o); }
  size_t oidx = ((size_t)(b*HEADS + h) * SEQ + i) * DH + d;
  qn[oidx] = f2bf(qv / fmaxf(sqrtf(qs), 1e-12f));
  kn[oidx] = f2bf(kv / fmaxf(sqrtf(ks), 1e-12f));
}

// ---------------- MFMA attn: 64 i-rows per wave (4 q-pairs), K loads amortized 4x ----
__global__ __launch_bounds__(256, 4) void k_attn(const u16* __restrict__ qb, const u16* __restrict__ kb,
                                                 u8* __restrict__ attn, float* __restrict__ rowsum,
                                                 int bh0) {
  __shared__ __align__(16) u8 buf[4][4][64][16];   // [wave][i-subtile][row][16B]
  __shared__ float reds[4][4][16];                 // [wave][i-subtile][l15]
  int t = threadIdx.x;
  int w = t >> 6, L = t & 63;
  int quad = L >> 4, l15 = L & 15;
  int bh_local = blockIdx.x >> 5;                  // 32 blocks per bh
  int bh = bh0 + bh_local;
  int i0blk = (blockIdx.x & 31) * 64;
  bf16x8 q0[4], q1[4];
#pragma unroll
  for (int s = 0; s < 4; s++) {
    const u16* qrow = qb + ((size_t)bh*SEQ + i0blk + s*16 + l15)*DH + quad*8;
    q0[s] = *(const bf16x8*)qrow;
    q1[s] = *(const bf16x8*)(qrow + 32);
  }
  const u16* kbase = kb + (size_t)bh*SEQ*DH;
  u8* abase = attn + ((size_t)bh_local << 22) + (size_t)(i0blk >> 4)*32768;
  float sa[4] = {0.f, 0.f, 0.f, 0.f};
  for (int g = 0; g < 8; g++) {
#pragma unroll 2
    for (int tt4 = 0; tt4 < 4; tt4++) {
      int j = w*512 + (g*4 + tt4)*16 + l15;
      const u16* krow = kbase + (size_t)j*DH + quad*8;
      bf16x8 a0 = *(const bf16x8*)krow;
      bf16x8 a1 = *(const bf16x8*)(krow + 32);
      int dl = ((tt4*2 + (quad>>1)) & 3)*16 + l15;
      int boff = (tt4>>1)*8 + (quad&1)*4;
#pragma unroll
      for (int s = 0; s < 4; s++) {
        floatx4 c = (floatx4){0.f,0.f,0.f,0.f};
        c = __builtin_amdgcn_mfma_f32_16x16x32_bf16(a0, q0[s], c, 0, 0, 0);
        c = __builtin_amdgcn_mfma_f32_16x16x32_bf16(a1, q1[s], c, 0, 0, 0);
        float e0 = exp2_raw(EXS * c[0]);
        float e1 = exp2_raw(EXS * c[1]);
        float e2 = exp2_raw(EXS * c[2]);
        float e3 = exp2_raw(EXS * c[3]);
        sa[s] += (e0 + e1) + (e2 + e3);          // all for the same i
        *(int*)&buf[w][s][dl][boff] = pk4_fp8(e0, e1, e2, e3);
      }
    }
#pragma unroll
    for (int s = 0; s < 4; s++) {
      uint4 v = *(const uint4*)&buf[w][s][L][0];
      *(uint4*)(abase + (size_t)s*32768 + (size_t)(w*8 + g)*1024 + (size_t)L*16) = v;
    }
  }
#pragma unroll
  for (int s = 0; s < 4; s++) {
    float v = sa[s];
    v += __shfl_xor(v, 16); v += __shfl_xor(v, 32);
    if (quad == 0) reds[w][s][l15] = v;
  }
  __syncthreads();
  if (t < 64)
    rowsum[(size_t)bh_local*SEQ + i0blk + t] =
        (reds[0][t >> 4][t & 15] + reds[1][t >> 4][t & 15]) +
        (reds[2][t >> 4][t & 15] + reds[3][t >> 4][t & 15]);
}

__global__ void k_zero(float* __restrict__ o, int n) {
  int i = blockIdx.x*256 + threadIdx.x; if (i < n) o[i] = 0.f;
}

// ---------------- step-0 shortcut: m1 = mag(xf + m0v) -> frag-tiled fp8 ----------------
__global__ __launch_bounds__(256) void k_step0(const float* __restrict__ xf, u8* __restrict__ mT,
                                               float m0v) {
  __shared__ __align__(16) u8 tile_t[64][72];   // [d][i_local], +8 pad
  int bh = blockIdx.x >> 5;       // 32 i-tiles per bh
  int kt2 = blockIdx.x & 31;
  int i0 = kt2 * 64;
  int b = bh >> 4, h = bh & (HEADS-1);
  int t = threadIdx.x;
  int row = t >> 2, part = t & 3;            // i-row in tile, 16-float d-part
  const float* xr = xf + ((size_t)b*SEQ + i0 + row)*NDIM + h*DH + part*16;
  float v[16]; float s = 0.f;
#pragma unroll
  for (int e = 0; e < 16; e++) { float u = xr[e] + m0v; v[e] = u; s += u*u; }
  s += __shfl_xor(s, 1); s += __shfl_xor(s, 2);
  float t2 = 0.5f*(1.0f + sqrtf(1.0f + s * INV_SCALE2));
  float inv = 1.0f/(2.0f*t2);
#pragma unroll
  for (int e = 0; e < 16; e += 4) {
    int p = pk4_fp8(v[e]*inv, v[e+1]*inv, v[e+2]*inv, v[e+3]*inv);
    tile_t[part*16 + e + 0][row] = (u8)(p & 255);
    tile_t[part*16 + e + 1][row] = (u8)((p >> 8) & 255);
    tile_t[part*16 + e + 2][row] = (u8)((p >> 16) & 255);
    tile_t[part*16 + e + 3][row] = (u8)((p >> 24) & 255);
  }
  __syncthreads();
  int nt = t >> 6, Lw = t & 63;
  i64 lo = *(const i64*)&tile_t[nt*16 + (Lw & 15)][(Lw >> 4)*8];
  i64 hi = *(const i64*)&tile_t[nt*16 + (Lw & 15)][32 + (Lw >> 4)*8];
  u8* dst = mT + ((size_t)bh << 17) + ((size_t)(nt*32 + kt2)*64 + Lw)*16;
  *(i64*)dst = lo;
  *(i64*)(dst + 8) = hi;
}

// ---------------- PERSISTENT fused mean-field steps: attn LDS-resident across all 7 steps ----
// 128 thr (2 waves), 64KB static LDS (2 i-tiles of attn), 2 blocks/CU -> grid 512 ALL
// co-resident (8 bh x 64 blocks). Per-bh atomic barrier between steps (release add +
// acquire spin). attn read from L3 ONCE instead of 7x (saves ~800MB). XCD affinity:
// blk&7 == bh_local -> all of a bh's blocks + its m exchange on one XCD L2.
__global__ __launch_bounds__(128) void k_steps(const u8* __restrict__ attn,
                                               const float* __restrict__ xf,
                                               const float* __restrict__ rowsum,
                                               u8* __restrict__ mTa, u8* __restrict__ mTb,
                                               float* __restrict__ out, int bh0,
                                               int* __restrict__ ctr) {
  __shared__ __align__(16) u8 at[65536];     // 2 x 32KB attn i-tiles (frag-tiled, linear)
  int t = threadIdx.x;
  int w = t >> 6, L = t & 63;
  int quad = L >> 4, l15 = L & 15;
  int bh_local = blockIdx.x & 7;             // == XCD under round-robin
  int slice = blockIdx.x >> 3;               // [0,64)
  int bh = bh0 + bh_local;
  int I = slice*2 + w;                       // this wave's i-tile [0,128)
  int b = bh >> 4, hh = bh & (HEADS-1);
  const u8* ab = attn + ((size_t)bh << 22) + (size_t)I*32768;
  // fill LDS once: 32KB per wave, linear frag-tile copy
  for (int it = 0; it < 32; it++)
    GLD16(ab + (size_t)it*1024 + (size_t)L*16, &at[w*32768 + it*1024]);
  __syncthreads();                           // drains vmcnt(0): attn resident

  const u8* bbA = mTa + ((size_t)bh << 17) + (size_t)L*16;
  const u8* bbB = mTb + ((size_t)bh << 17) + (size_t)L*16;
  int ibase = I*16 + quad*4;
  for (int s = 1; s < NSTEPS; s++) {
    const u8* bb = (s & 1) ? bbA : bbB;
    floatx4 acc[4];
#pragma unroll
    for (int j = 0; j < 4; j++) acc[j] = (floatx4){0.f,0.f,0.f,0.f};
#pragma unroll 4
    for (int kt2 = 0; kt2 < 32; kt2++) {
      i64x2 a  = *(const i64x2*)&at[w*32768 + kt2*1024 + L*16];
      i64x2 b0 = *(const i64x2*)(bb + (size_t)kt2*1024);
      i64x2 b1 = *(const i64x2*)(bb + (size_t)(32 + kt2)*1024);
      i64x2 b2 = *(const i64x2*)(bb + (size_t)(64 + kt2)*1024);
      i64x2 b3 = *(const i64x2*)(bb + (size_t)(96 + kt2)*1024);
      acc[0] = __builtin_amdgcn_mfma_f32_16x16x32_fp8_fp8(a.x, b0.x, acc[0], 0, 0, 0);
      acc[1] = __builtin_amdgcn_mfma_f32_16x16x32_fp8_fp8(a.x, b1.x, acc[1], 0, 0, 0);
      acc[2] = __builtin_amdgcn_mfma_f32_16x16x32_fp8_fp8(a.x, b2.x, acc[2], 0, 0, 0);
      acc[3] = __builtin_amdgcn_mfma_f32_16x16x32_fp8_fp8(a.x, b3.x, acc[3], 0, 0, 0);
      acc[0] = __builtin_amdgcn_mfma_f32_16x16x32_fp8_fp8(a.y, b0.y, acc[0], 0, 0, 0);
      acc[1] = __builtin_amdgcn_mfma_f32_16x16x32_fp8_fp8(a.y, b1.y, acc[1], 0, 0, 0);
      acc[2] = __builtin_amdgcn_mfma_f32_16x16x32_fp8_fp8(a.y, b2.y, acc[2], 0, 0, 0);
      acc[3] = __builtin_amdgcn_mfma_f32_16x16x32_fp8_fp8(a.y, b3.y, acc[3], 0, 0, 0);
    }
    float th[4][4]; float invr[4];
#pragma unroll
    for (int reg = 0; reg < 4; reg++) {
      float sinv = 1.0f / rowsum[(size_t)bh*SEQ + ibase + reg];
      size_t xoff = ((size_t)b*SEQ + ibase + reg)*NDIM + hh*DH + l15;
      float sq = 0.f;
#pragma unroll
      for (int nt = 0; nt < 4; nt++) {
        float v = acc[nt][reg]*sinv + xf[xoff + nt*16];
        th[nt][reg] = v; sq += v*v;
      }
      sq += __shfl_xor(sq, 1); sq += __shfl_xor(sq, 2); sq += __shfl_xor(sq, 4); sq += __shfl_xor(sq, 8);
      float tt2 = 0.5f*(1.0f + sqrtf(1.0f + sq * INV_SCALE2));
      invr[reg] = 1.0f/(2.0f*tt2);
    }
    if (s == NSTEPS-1) {
#pragma unroll
      for (int reg = 0; reg < 4; reg++) {
        size_t ooff = ((size_t)b*SEQ + ibase + reg)*NDIM + hh*DH + l15;
#pragma unroll
        for (int nt = 0; nt < 4; nt++) out[ooff + nt*16] = th[nt][reg]*invr[reg];
      }
    } else {
      u8* dst = (s & 1) ? mTb : mTa;
      int kt2o = I >> 2;
      int hf = (I >> 1) & 1;
      int lhi = ((I & 1)*2 + (quad >> 1)) & 3;
      u8* ob = dst + ((size_t)bh << 17) + (size_t)(lhi*16 + l15)*16 + hf*8 + (quad & 1)*4;
#pragma unroll
      for (int nt = 0; nt < 4; nt++) {
        int p = pk4_fp8(th[nt][0]*invr[0], th[nt][1]*invr[1],
                        th[nt][2]*invr[2], th[nt][3]*invr[3]);
        *(int*)(ob + (size_t)(nt*32 + kt2o)*1024) = p;
      }
      // ---- per-bh barrier: all 64 blocks must finish step s before any starts s+1 ----
      __threadfence();             // release this thread's m writes (agent scope)
      __syncthreads();             // all threads in block released
      if (t == 0) {
        __hip_atomic_fetch_add(&ctr[bh_local], 1, __ATOMIC_RELEASE, __HIP_MEMORY_SCOPE_AGENT);
        while (__hip_atomic_load(&ctr[bh_local], __ATOMIC_ACQUIRE, __HIP_MEMORY_SCOPE_AGENT) < 64*s)
          __builtin_amdgcn_s_sleep(8);
      }
      __syncthreads();             // block proceeds after t0's acquire (L1 invalidated)
    }
  }
}

// ---------------- fallback per-step kernel (R11 form, CH != 32 path) ----------------
template<int LAST>
__global__ __launch_bounds__(256) void k_step(const u8* __restrict__ attn, const u8* __restrict__ mT_in,
                                              const float* __restrict__ xf,
                                              const float* __restrict__ rowsum,
                                              u8* __restrict__ mT_out,
                                              float* __restrict__ out, int bh0, int CH) {
  int t = threadIdx.x;
  int w = t >> 6, L = t & 63;
  int quad = L >> 4, l15 = L & 15;
  int blk = blockIdx.x;
  int bh_local, I4;
  if (CH >= 8) {
    int gpb = CH >> 3;
    int q = blk >> 3;
    bh_local = (blk & 7) + 8 * (q % gpb);
    I4 = q / gpb;
  } else {
    bh_local = blk >> 5;
    I4 = blk & 31;
  }
  int bh = bh0 + bh_local;
  int I = I4*4 + w;
  int b = bh >> 4, hh = bh & (HEADS-1);
  const u8* ab = attn + ((size_t)bh_local << 22) + (size_t)I*32768 + (size_t)L*16;
  const u8* bb = mT_in + ((size_t)bh << 17) + (size_t)L*16;
  floatx4 acc[4];
#pragma unroll
  for (int j = 0; j < 4; j++) acc[j] = (floatx4){0.f,0.f,0.f,0.f};

#pragma unroll 4
  for (int kt2 = 0; kt2 < 32; kt2++) {
    i64x2 a  = *(const i64x2*)(ab + (size_t)kt2*1024);
    i64x2 b0 = *(const i64x2*)(bb + (size_t)kt2*1024);
    i64x2 b1 = *(const i64x2*)(bb + (size_t)(32 + kt2)*1024);
    i64x2 b2 = *(const i64x2*)(bb + (size_t)(64 + kt2)*1024);
    i64x2 b3 = *(const i64x2*)(bb + (size_t)(96 + kt2)*1024);
    acc[0] = __builtin_amdgcn_mfma_f32_16x16x32_fp8_fp8(a.x, b0.x, acc[0], 0, 0, 0);
    acc[1] = __builtin_amdgcn_mfma_f32_16x16x32_fp8_fp8(a.x, b1.x, acc[1], 0, 0, 0);
    acc[2] = __builtin_amdgcn_mfma_f32_16x16x32_fp8_fp8(a.x, b2.x, acc[2], 0, 0, 0);
    acc[3] = __builtin_amdgcn_mfma_f32_16x16x32_fp8_fp8(a.x, b3.x, acc[3], 0, 0, 0);
    acc[0] = __builtin_amdgcn_mfma_f32_16x16x32_fp8_fp8(a.y, b0.y, acc[0], 0, 0, 0);
    acc[1] = __builtin_amdgcn_mfma_f32_16x16x32_fp8_fp8(a.y, b1.y, acc[1], 0, 0, 0);
    acc[2] = __builtin_amdgcn_mfma_f32_16x16x32_fp8_fp8(a.y, b2.y, acc[2], 0, 0, 0);
    acc[3] = __builtin_amdgcn_mfma_f32_16x16x32_fp8_fp8(a.y, b3.y, acc[3], 0, 0, 0);
  }
  int ibase = I*16 + quad*4;
  float th[4][4]; float invr[4];
#pragma unroll
  for (int reg = 0; reg < 4; reg++) {
    float sinv = 1.0f / rowsum[(size_t)bh_local*SEQ + ibase + reg];
    size_t xoff = ((size_t)b*SEQ + ibase + reg)*NDIM + hh*DH + l15;
    float s = 0.f;
#pragma unroll
    for (int nt = 0; nt < 4; nt++) {
      float v = acc[nt][reg]*sinv + xf[xoff + nt*16];
      th[nt][reg] = v; s += v*v;
    }
    s += __shfl_xor(s, 1); s += __shfl_xor(s, 2); s += __shfl_xor(s, 4); s += __shfl_xor(s, 8);
    float tt2 = 0.5f*(1.0f + sqrtf(1.0f + s * INV_SCALE2));
    invr[reg] = 1.0f/(2.0f*tt2);
  }
  if (LAST) {
#pragma unroll
    for (int reg = 0; reg < 4; reg++) {
      size_t ooff = ((size_t)b*SEQ + ibase + reg)*NDIM + hh*DH + l15;
#pragma unroll
      for (int nt = 0; nt < 4; nt++) out[ooff + nt*16] = th[nt][reg]*invr[reg];
    }
  } else {
    int kt2o = I >> 2;
    int hf = (I >> 1) & 1;
    int lhi = ((I & 1)*2 + (quad >> 1)) & 3;
    u8* ob = mT_out + ((size_t)bh << 17) + (size_t)(lhi*16 + l15)*16 + hf*8 + (quad & 1)*4;
#pragma unroll
    for (int nt = 0; nt < 4; nt++) {
      int p = pk4_fp8(th[nt][0]*invr[0], th[nt][1]*invr[1],
                      th[nt][2]*invr[2], th[nt][3]*invr[3]);
      *(int*)(ob + (size_t)(nt*32 + kt2o)*1024) = p;
    }
  }
}

extern "C" void kernel_launch(void* const* d_in, const int* in_sizes, int n_in,
                              void* d_out, int out_size, void* d_ws, size_t ws_size,
                              hipStream_t stream) {
  const void* x    = d_in[0];
  const void* w_qk = d_in[1];
  const void* w1   = d_in[2];
  const void* w2   = d_in[3];
  float* out = (float*)d_out;

  const size_t E = (size_t)BQ*SEQ*NDIM;     // 4,194,304
  const int NW_QK = 2*NDIM*NDIM;
  const int NW1   = 4*NDIM*NDIM;
  const int NW2   = 4*NDIM*NDIM;

  char* ws = (char*)d_ws;
  size_t off = 0;
  auto alloc = [&](size_t bytes) { void* p = ws + off; off += (bytes + 255) & ~255ull; return p; };
  int*  flag = (int*)alloc(256);
  u16*  xs  = (u16*)alloc(E*2);             // scaled-normalized x (bf16)
  u16*  qb  = (u16*)alloc(E*2);             // q normalized [B,H,N,DH] bf16
  u16*  kb  = (u16*)alloc(E*2);
  float* xf = (float*)alloc(E*4);           // external field fp32
  u8*   mT  = (u8*)alloc(E*2);              // two fp8 m-buffers, frag-tiled
  float* rsum = (float*)alloc((size_t)BQ*HEADS*SEQ*4);  // softmax denominators
  int*  ctr = (int*)alloc(256);             // persistent-kernel barrier counters (8 x 4 groups)
  u8*   mTa = mT;
  u8*   mTb = mT + E;

  char* S = ws + off;
  size_t availS = (ws_size > off) ? ws_size - off : 0;
  // S-region temporal plan: [wqkb|qkraw] -> [.|.|w1b|w2b|hbuf|pbuf] -> [attn chunk fp8]
  u16* wqkb  = (u16*)(S);
  u16* qkraw = (u16*)(S + 4194304);
  u16* w1b   = (u16*)(S + 20971520);
  u16* w2b   = (u16*)(S + 29360128);
  u16* hbuf  = (u16*)(S + 37748736);
  u8*  attn  = (u8*)(S);
  u16* xb    = (u16*)mT;                     // alias (2E bytes): dead before k_step0

  const int rcs[6] = {4096, 2048, 1024, 512, 256, 128};
  int RC = 0;
  for (int i = 0; i < 6; i++)
    if (37748736ull + (size_t)rcs[i]*4096*2 <= availS) { RC = rcs[i]; break; }
  const int chs[6] = {32, 16, 8, 4, 2, 1};
  int CH = 0;
  for (int i = 0; i < 6; i++)
    if ((size_t)chs[i]*SEQ*SEQ <= availS) { CH = chs[i]; break; }
  if (RC == 0 || CH == 0) {
    k_zero<<<(out_size+255)/256, 256, 0, stream>>>(out, out_size);
    return;
  }
  // split-K partial buffer (2 x RC x NDIM fp32) after hbuf; fallback if it doesn't fit
  size_t pboff = 37748736ull + (size_t)RC*4096*2;
  int use_ksp = (pboff + (size_t)RC*NDIM*8 <= availS) ? 1 : 0;
  float* pbuf = (float*)(S + pboff);

  const int M = BQ*SEQ;  // 4096

  // dtype probe + canonical bf16 conversion
  k_flag0<<<1, 64, 0, stream>>>(flag);
  k_probe<<<256, 256, 0, stream>>>((const u16*)x, flag);
  k_convert<<<(int)(E/256), 256, 0, stream>>>(x, xb, flag, (int)E);
  k_convert<<<NW_QK/256, 256, 0, stream>>>(w_qk, wqkb, flag, NW_QK);
  k_convert<<<NW1/256, 256, 0, stream>>>(w1, w1b, flag, NW1);
  k_convert<<<NW2/256, 256, 0, stream>>>(w2, w2b, flag, NW2);

  k_norm_scale<<<M, 256, 0, stream>>>(xb, xs);
  { dim3 g(M/128, 2048/128); k_gemm<1,0,0><<<g, 256, 0, stream>>>(xs, wqkb, nullptr, qkraw, nullptr, M, 2048, 1024); }
  k_headnorm<<<M*HEADS, 64, 0, stream>>>(qkraw, qb, kb);

  for (int c = 0; c < M/RC; c++) {
    const u16* xsc = xs + (size_t)c*RC*NDIM;
    { dim3 g(RC/128, 4096/128); k_gemm<1,1,0><<<g, 256, 0, stream>>>(xsc, w1b, nullptr, hbuf, nullptr, RC, 4096, 1024); }
    if (use_ksp) {
      dim3 g(RC/128, 1024/128, 2);
      k_gemm_w2ks<<<g, 512, 0, stream>>>(hbuf, w2b, pbuf, RC, 1024, 4096);
      int n = RC*NDIM;
      k_w2red<<<n/1024, 256, 0, stream>>>(pbuf, pbuf + n, xsc, xf + (size_t)c*RC*NDIM, n);
    } else {
      dim3 g(RC/128, 1024/128);
      k_gemm_w2<<<g, 512, 0, stream>>>(hbuf, w2b, xf + (size_t)c*RC*NDIM, xsc, RC, 1024, 4096);
    }
  }

  // step 0 closed form: m1 = mag(xf + m0v) since normalized attn rows sum to 1 and m0 is constant
  float t0 = 0.5f*(1.0f + sqrtf(1.0f + 64.0f/511.0f));
  float m0v = 1.0f/(2.0f*t0);
  k_step0<<<BQ*HEADS*32, 256, 0, stream>>>(xf, mTa, m0v);

  if (CH == 32) {
    // persistent fused path: attn for ALL 32 bh computed once, then 4 persistent
    // launches (8 bh each, 512 co-resident blocks) run all 7 steps with attn in LDS.
    k_attn<<<32*32, 256, 0, stream>>>(qb, kb, attn, rsum, 0);
    k_zero<<<1, 64, 0, stream>>>((float*)ctr, 64);
    for (int g = 0; g < 4; g++)
      k_steps<<<512, 128, 0, stream>>>(attn, xf, rsum, mTa, mTb, out, g*8, ctr + g*8);
  } else {
    for (int c0 = 0; c0 < BQ*HEADS; c0 += CH) {
      k_attn<<<CH*32, 256, 0, stream>>>(qb, kb, attn, rsum, c0);
      for (int s = 1; s < NSTEPS; s++) {
        u8* src = (s & 1) ? mTa : mTb;
        u8* dst = (s & 1) ? mTb : mTa;
        if (s == NSTEPS-1)
          k_step<1><<<CH*32, 256, 0, stream>>>(attn, src, xf, rsum, nullptr, out, c0, CH);
        else
          k_step<0><<<CH*32, 256, 0, stream>>>(attn, src, xf, rsum, dst, nullptr, c0, CH);
      }
    }
  }
}

// Round 14
// 518.762 us; speedup vs baseline: 3.3852x; 3.3852x over previous
//
#include <hip/hip_runtime.h>
#include <hip/hip_bf16.h>
#include <math.h>

#define BQ 2
#define SEQ 2048
#define NDIM 1024
#define HEADS 16
#define DH 64
#define NSTEPS 8
#define SCALE 22.60530911f      /* sqrt(511) */
#define SCALE_HEAD 5.567764363f /* sqrt(31)  */
#define INV_SCALE2 (1.0f/511.0f)
#define EXS 8.0325527f          /* SCALE_HEAD * log2(e) */

typedef unsigned short u16;
typedef unsigned char u8;
typedef long long i64;
typedef __attribute__((ext_vector_type(8))) short bf16x8;   // 8 bf16 = 4 VGPR
typedef __attribute__((ext_vector_type(4))) float floatx4;  // MFMA 16x16 acc
typedef __attribute__((ext_vector_type(2))) long long i64x2; // 16B = two fp8 K=32 frags

__device__ __forceinline__ float bf2f(u16 u) {
  union { unsigned int i; float f; } v; v.i = ((unsigned int)u) << 16; return v.f;
}
__device__ __forceinline__ u16 f2bf(float f) {
  union { float f; unsigned int i; } v; v.f = f;
  unsigned int x = v.i;
  return (u16)((x + 0x7fffu + ((x >> 16) & 1u)) >> 16);
}
// raw v_exp_f32 via compiler-modeled builtin (inputs bounded here)
#if __has_builtin(__builtin_amdgcn_exp2f)
__device__ __forceinline__ float exp2_raw(float x) { return __builtin_amdgcn_exp2f(x); }
#else
__device__ __forceinline__ float exp2_raw(float x) { return exp2f(x); }
#endif
#if __has_builtin(__builtin_amdgcn_rcpf)
__device__ __forceinline__ float rcp_raw(float x) { return __builtin_amdgcn_rcpf(x); }
#else
__device__ __forceinline__ float rcp_raw(float x) { return 1.0f/x; }
#endif

// tanh-approx GELU: max |diff vs exact| ~5e-4, below bf16 output quantization.
__device__ __forceinline__ float gelu_tanh(float v) {
  float v2 = v*v;
  float u = v * __builtin_fmaf(0.0356774081f, v2, 0.7978845608f);
  float t = exp2_raw(2.8853900817779268f * u);   // e^{2u}, u in [-5.6, 5.6]
  float th = (t - 1.0f) * rcp_raw(t + 1.0f);
  return 0.5f * v * (1.0f + th);
}

// packed fp8 conversion via HW cvt (gfx950 native fp8 = OCP e4m3fn)
__device__ __forceinline__ int pk4_fp8(float a, float b, float c, float d) {
  int p = 0;
  p = __builtin_amdgcn_cvt_pk_fp8_f32(a, b, p, false);
  p = __builtin_amdgcn_cvt_pk_fp8_f32(c, d, p, true);
  return p;
}

// async global->LDS, 16B per lane; LDS dest = wave-uniform base + lane*16
#define GLD16(gp, lp) __builtin_amdgcn_global_load_lds( \
    (__attribute__((address_space(1))) void*)(gp),      \
    (__attribute__((address_space(3))) void*)(lp), 16, 0, 0)

/* ===================== FRAG-TILED OPERAND LAYOUTS =====================
 * A (attn, per bh_local, 4MB): element e_raw[i][j]:
 *   I=i>>4, kt2=j>>6, hf=(j>>5)&1, Lhi=(j>>3)&3, e=j&7, l15=i&15
 *   addr = ((I*32 + kt2)*64 + Lhi*16 + l15)*16 + hf*8 + e
 * B (m, per bh, 128KB): element m[d][j]:
 *   nt=d>>4, l15=d&15, kt2=j>>6, hf=(j>>5)&1, Lhi=(j>>3)&3, e=j&7
 *   addr = ((nt*32 + kt2)*64 + Lhi*16 + l15)*16 + hf*8 + e
 * Lane L of an MFMA then loads its frag as one dwordx4 at base + L*16. */

// ---------------- dtype probe: flag=1 if input is fp32 ----------------
__global__ void k_flag0(int* flag) { if (threadIdx.x == 0 && blockIdx.x == 0) *flag = 0; }

__global__ __launch_bounds__(256) void k_probe(const u16* __restrict__ x, int* __restrict__ flag) {
  int i = blockIdx.x * 256 + threadIdx.x;
  float v = bf2f(x[i]);
  if (!(fabsf(v) <= 1e4f)) atomicOr(flag, 1);
}

__global__ __launch_bounds__(256) void k_convert(const void* __restrict__ in, u16* __restrict__ outb,
                                                 const int* __restrict__ flag, int n) {
  int i = blockIdx.x * 256 + threadIdx.x;
  if (i >= n) return;
  if (*flag) outb[i] = f2bf(((const float*)in)[i]);
  else       outb[i] = ((const u16*)in)[i];
}

// ---------------- normalize + scale x -> xs (bf16) ----------------
__global__ __launch_bounds__(256) void k_norm_scale(const u16* __restrict__ x, u16* __restrict__ xs) {
  __shared__ float red[256];
  int row = blockIdx.x;
  const u16* xr = x + (size_t)row * NDIM;
  u16* orow = xs + (size_t)row * NDIM;
  int t = threadIdx.x;
  float vals[4]; float s = 0.f;
#pragma unroll
  for (int e = 0; e < 4; e++) { float v = bf2f(xr[t + 256*e]); vals[e] = v; s += v*v; }
  red[t] = s; __syncthreads();
  for (int o = 128; o > 0; o >>= 1) { if (t < o) red[t] += red[t+o]; __syncthreads(); }
  float sc = SCALE / fmaxf(sqrtf(red[0]), 1e-12f);
#pragma unroll
  for (int e = 0; e < 4; e++) orow[t + 256*e] = f2bf(vals[e] * sc);
}

// ---------------- MFMA GEMM (bf16), BK=64 via dual 32-col slabs ----------------
template<int OUT_BF16, int GELU, int ADDSRC>
__global__ __launch_bounds__(256) void k_gemm(const u16* __restrict__ A, const u16* __restrict__ W,
                                              float* __restrict__ Cf, u16* __restrict__ Cb,
                                              const u16* __restrict__ addsrc, int M, int N, int K) {
  __shared__ __align__(16) u16 As[2][128*32];
  __shared__ __align__(16) u16 Bs[2][128*32];
  int t = threadIdx.x;
  int w = t >> 6, L = t & 63;
  int quad = L >> 4, l15 = L & 15;
  int wr = w >> 1, wc = w & 1;
  int bm = blockIdx.x * 128, bn = blockIdx.y * 128;
  int srow = L >> 2, scol = (L & 3) * 8;
  floatx4 acc[4][4];
#pragma unroll
  for (int i = 0; i < 4; i++)
#pragma unroll
    for (int j = 0; j < 4; j++) acc[i][j] = (floatx4){0.f,0.f,0.f,0.f};

  for (int k0 = 0; k0 < K; k0 += 64) {
#pragma unroll
    for (int c = 0; c < 2; c++) {
      int r = c*64 + w*16 + srow;
      const u16* ap = A + (size_t)(bm + r)*K + k0 + scol;
      const u16* wp = W + (size_t)(bn + r)*K + k0 + scol;
      GLD16(ap,      &As[0][(c*64 + w*16)*32]);
      GLD16(ap + 32, &As[1][(c*64 + w*16)*32]);
      GLD16(wp,      &Bs[0][(c*64 + w*16)*32]);
      GLD16(wp + 32, &Bs[1][(c*64 + w*16)*32]);
    }
    __syncthreads();
#pragma unroll
    for (int s = 0; s < 2; s++) {
      bf16x8 af[4], bfr[4];
#pragma unroll
      for (int mt = 0; mt < 4; mt++) af[mt]  = *(const bf16x8*)&As[s][(wr*64 + mt*16 + l15)*32 + quad*8];
#pragma unroll
      for (int nt = 0; nt < 4; nt++) bfr[nt] = *(const bf16x8*)&Bs[s][(wc*64 + nt*16 + l15)*32 + quad*8];
#pragma unroll
      for (int mt = 0; mt < 4; mt++)
#pragma unroll
        for (int nt = 0; nt < 4; nt++)
          acc[mt][nt] = __builtin_amdgcn_mfma_f32_16x16x32_bf16(af[mt], bfr[nt], acc[mt][nt], 0, 0, 0);
    }
    __syncthreads();
  }
#pragma unroll
  for (int mt = 0; mt < 4; mt++)
#pragma unroll
    for (int reg = 0; reg < 4; reg++) {
      int m = bm + wr*64 + mt*16 + quad*4 + reg;
      size_t rowoff = (size_t)m * N;
#pragma unroll
      for (int nt = 0; nt < 4; nt++) {
        int n = bn + wc*64 + nt*16 + l15;
        float v = acc[mt][nt][reg];
        if (GELU) v = gelu_tanh(v);
        if (ADDSRC) v += bf2f(addsrc[rowoff + n]);
        if (OUT_BF16) Cb[rowoff + n] = f2bf(v);
        else Cf[rowoff + n] = v;
      }
    }
}

// ---------------- w2 GEMM fallback: intra-block split-K only (1 block/CU) ----------
__global__ __launch_bounds__(512) void k_gemm_w2(const u16* __restrict__ A, const u16* __restrict__ W,
                                                 float* __restrict__ Cf,
                                                 const u16* __restrict__ addsrc, int M, int N, int K) {
  __shared__ __align__(16) u16 As[2][128*32];
  __shared__ __align__(16) u16 Bs[2][128*32];
  int t = threadIdx.x;
  int g = t >> 8;
  int tg = t & 255;
  int w = tg >> 6;
  int L = t & 63;
  int quad = L >> 4, l15 = L & 15;
  int wr = w >> 1, wc = w & 1;
  int bm = blockIdx.x * 128, bn = blockIdx.y * 128;
  int srow = L >> 2, scol = (L & 3) * 8;
  int kg0 = g * (K >> 1);
  floatx4 acc[4][4];
#pragma unroll
  for (int i = 0; i < 4; i++)
#pragma unroll
    for (int j = 0; j < 4; j++) acc[i][j] = (floatx4){0.f,0.f,0.f,0.f};

  for (int k0 = 0; k0 < (K >> 1); k0 += 32) {
    int kk = kg0 + k0;
#pragma unroll
    for (int c = 0; c < 2; c++) {
      int r = c*64 + w*16 + srow;
      GLD16(A + (size_t)(bm + r)*K + kk + scol, &As[g][(c*64 + w*16)*32]);
      GLD16(W + (size_t)(bn + r)*K + kk + scol, &Bs[g][(c*64 + w*16)*32]);
    }
    __syncthreads();
    bf16x8 af[4], bfr[4];
#pragma unroll
    for (int mt = 0; mt < 4; mt++) af[mt]  = *(const bf16x8*)&As[g][(wr*64 + mt*16 + l15)*32 + quad*8];
#pragma unroll
    for (int nt = 0; nt < 4; nt++) bfr[nt] = *(const bf16x8*)&Bs[g][(wc*64 + nt*16 + l15)*32 + quad*8];
#pragma unroll
    for (int mt = 0; mt < 4; mt++)
#pragma unroll
      for (int nt = 0; nt < 4; nt++)
        acc[mt][nt] = __builtin_amdgcn_mfma_f32_16x16x32_bf16(af[mt], bfr[nt], acc[mt][nt], 0, 0, 0);
    __syncthreads();
  }
  float* LFA = (float*)&As[0][0];
  float* LFB = (float*)&Bs[0][0];
#pragma unroll
  for (int r = 0; r < 2; r++) {
    float* myW = g ? LFA : LFB;
    int mtW = g ? r : (2 + r);
#pragma unroll
    for (int reg = 0; reg < 4; reg++)
#pragma unroll
      for (int nt = 0; nt < 4; nt++)
        myW[(wr*16 + quad*4 + reg)*128 + wc*64 + nt*16 + l15] = acc[mtW][nt][reg];
    __syncthreads();
    float* myR = g ? LFB : LFA;
    int mtS = g ? (2 + r) : r;
#pragma unroll
    for (int reg = 0; reg < 4; reg++) {
      int m = bm + wr*64 + mtS*16 + quad*4 + reg;
      size_t rowoff = (size_t)m * N;
#pragma unroll
      for (int nt = 0; nt < 4; nt++) {
        int n = bn + wc*64 + nt*16 + l15;
        float v = acc[mtS][nt][reg] + myR[(wr*16 + quad*4 + reg)*128 + wc*64 + nt*16 + l15];
        v += bf2f(addsrc[rowoff + n]);
        Cf[rowoff + n] = v;
      }
    }
    __syncthreads();
  }
}

// ---------------- w2 GEMM: inter-block (z=2) + intra-block (g=2) split-K ----------
__global__ __launch_bounds__(512) void k_gemm_w2ks(const u16* __restrict__ A, const u16* __restrict__ W,
                                                   float* __restrict__ pbuf, int M, int N, int K) {
  __shared__ __align__(16) u16 As[2][128*32];
  __shared__ __align__(16) u16 Bs[2][128*32];
  int t = threadIdx.x;
  int g = t >> 8;                 // K-quarter group within block (wave-uniform)
  int tg = t & 255;
  int w = tg >> 6;
  int L = t & 63;
  int quad = L >> 4, l15 = L & 15;
  int wr = w >> 1, wc = w & 1;
  int bm = blockIdx.x * 128, bn = blockIdx.y * 128;
  int z = blockIdx.z;             // K-half
  int srow = L >> 2, scol = (L & 3) * 8;
  int kg0 = z * (K >> 1) + g * (K >> 2);
  floatx4 acc[4][4];
#pragma unroll
  for (int i = 0; i < 4; i++)
#pragma unroll
    for (int j = 0; j < 4; j++) acc[i][j] = (floatx4){0.f,0.f,0.f,0.f};

  for (int k0 = 0; k0 < (K >> 2); k0 += 32) {
    int kk = kg0 + k0;
#pragma unroll
    for (int c = 0; c < 2; c++) {
      int r = c*64 + w*16 + srow;
      GLD16(A + (size_t)(bm + r)*K + kk + scol, &As[g][(c*64 + w*16)*32]);
      GLD16(W + (size_t)(bn + r)*K + kk + scol, &Bs[g][(c*64 + w*16)*32]);
    }
    __syncthreads();
    bf16x8 af[4], bfr[4];
#pragma unroll
    for (int mt = 0; mt < 4; mt++) af[mt]  = *(const bf16x8*)&As[g][(wr*64 + mt*16 + l15)*32 + quad*8];
#pragma unroll
    for (int nt = 0; nt < 4; nt++) bfr[nt] = *(const bf16x8*)&Bs[g][(wc*64 + nt*16 + l15)*32 + quad*8];
#pragma unroll
    for (int mt = 0; mt < 4; mt++)
#pragma unroll
      for (int nt = 0; nt < 4; nt++)
        acc[mt][nt] = __builtin_amdgcn_mfma_f32_16x16x32_bf16(af[mt], bfr[nt], acc[mt][nt], 0, 0, 0);
    __syncthreads();
  }
  float* LFA = (float*)&As[0][0];
  float* LFB = (float*)&Bs[0][0];
  float* pb = pbuf + (size_t)z * M * N;
#pragma unroll
  for (int r = 0; r < 2; r++) {
    float* myW = g ? LFA : LFB;
    int mtW = g ? r : (2 + r);
#pragma unroll
    for (int reg = 0; reg < 4; reg++)
#pragma unroll
      for (int nt = 0; nt < 4; nt++)
        myW[(wr*16 + quad*4 + reg)*128 + wc*64 + nt*16 + l15] = acc[mtW][nt][reg];
    __syncthreads();
    float* myR = g ? LFB : LFA;
    int mtS = g ? (2 + r) : r;
#pragma unroll
    for (int reg = 0; reg < 4; reg++) {
      int m = bm + wr*64 + mtS*16 + quad*4 + reg;
      size_t rowoff = (size_t)m * N;
#pragma unroll
      for (int nt = 0; nt < 4; nt++) {
        int n = bn + wc*64 + nt*16 + l15;
        pb[rowoff + n] = acc[mtS][nt][reg] + myR[(wr*16 + quad*4 + reg)*128 + wc*64 + nt*16 + l15];
      }
    }
    __syncthreads();
  }
}

// reduce: xf = p0 + p1 + bf16(xs); vectorized x4
__global__ __launch_bounds__(256) void k_w2red(const float* __restrict__ p0, const float* __restrict__ p1,
                                               const u16* __restrict__ xs, float* __restrict__ xf, int n) {
  int i = (blockIdx.x * 256 + threadIdx.x) * 4;
  if (i >= n) return;
  float4 a = *(const float4*)(p0 + i);
  float4 b = *(const float4*)(p1 + i);
  ushort4 s = *(const ushort4*)(xs + i);
  float4 o;
  o.x = a.x + b.x + bf2f(s.x);
  o.y = a.y + b.y + bf2f(s.y);
  o.z = a.z + b.z + bf2f(s.z);
  o.w = a.w + b.w + bf2f(s.w);
  *(float4*)(xf + i) = o;
}

// ---------------- per-head normalize q,k -> [B,H,N,DH] bf16 ----------------
__global__ __launch_bounds__(64) void k_headnorm(const u16* __restrict__ qkraw,
                                                 u16* __restrict__ qn, u16* __restrict__ kn) {
  int blk = blockIdx.x;
  int h = blk & (HEADS-1); int bi = blk >> 4;
  int b = bi >> 11, i = bi & (SEQ-1);
  int d = threadIdx.x;
  const u16* base = qkraw + (size_t)bi * (2*NDIM);
  float qv = bf2f(base[h*DH + d]);
  float kv = bf2f(base[NDIM + h*DH + d]);
  float qs = qv*qv, ks = kv*kv;
#pragma unroll
  for (int o = 32; o > 0; o >>= 1) { qs += __shfl_xor(qs, o); ks += __shfl_xor(ks, o); }
  size_t oidx = ((size_t)(b*HEADS + h) * SEQ + i) * DH + d;
  qn[oidx] = f2bf(qv / fmaxf(sqrtf(qs), 1e-12f));
  kn[oidx] = f2bf(kv / fmaxf(sqrtf(ks), 1e-12f));
}

// ---------------- MFMA attn: 64 i-rows per wave + XCD-affinity remap ----------------
// T1 applied (3rd kernel): blocks of one bh satisfy blk%8 == bh_local%8 -> same XCD.
// K matrix (256KB/bh) + Q now L2-resident per XCD (2MB for 4 bh) instead of each
// XCD pulling every bh's K from L3 independently.
__global__ __launch_bounds__(256, 4) void k_attn(const u16* __restrict__ qb, const u16* __restrict__ kb,
                                                 u8* __restrict__ attn, float* __restrict__ rowsum,
                                                 int bh0, int CH) {
  __shared__ __align__(16) u8 buf[4][4][64][16];   // [wave][i-subtile][row][16B]
  __shared__ float reds[4][4][16];                 // [wave][i-subtile][l15]
  int t = threadIdx.x;
  int w = t >> 6, L = t & 63;
  int quad = L >> 4, l15 = L & 15;
  int blk = blockIdx.x;
  int bh_local, islice;
  if (CH >= 8) {
    int gpb = CH >> 3;                             // bh-groups per XCD
    int q = blk >> 3;
    bh_local = (blk & 7) + 8 * (q % gpb);          // blk%8 == bh_local%8 == XCD
    islice = q / gpb;                              // [0,32)
  } else {
    bh_local = blk >> 5;
    islice = blk & 31;
  }
  int bh = bh0 + bh_local;
  int i0blk = islice * 64;
  bf16x8 q0[4], q1[4];
#pragma unroll
  for (int s = 0; s < 4; s++) {
    const u16* qrow = qb + ((size_t)bh*SEQ + i0blk + s*16 + l15)*DH + quad*8;
    q0[s] = *(const bf16x8*)qrow;
    q1[s] = *(const bf16x8*)(qrow + 32);
  }
  const u16* kbase = kb + (size_t)bh*SEQ*DH;
  u8* abase = attn + ((size_t)bh_local << 22) + (size_t)(i0blk >> 4)*32768;
  float sa[4] = {0.f, 0.f, 0.f, 0.f};
  for (int g = 0; g < 8; g++) {
#pragma unroll 2
    for (int tt4 = 0; tt4 < 4; tt4++) {
      int j = w*512 + (g*4 + tt4)*16 + l15;
      const u16* krow = kbase + (size_t)j*DH + quad*8;
      bf16x8 a0 = *(const bf16x8*)krow;
      bf16x8 a1 = *(const bf16x8*)(krow + 32);
      int dl = ((tt4*2 + (quad>>1)) & 3)*16 + l15;
      int boff = (tt4>>1)*8 + (quad&1)*4;
#pragma unroll
      for (int s = 0; s < 4; s++) {
        floatx4 c = (floatx4){0.f,0.f,0.f,0.f};
        c = __builtin_amdgcn_mfma_f32_16x16x32_bf16(a0, q0[s], c, 0, 0, 0);
        c = __builtin_amdgcn_mfma_f32_16x16x32_bf16(a1, q1[s], c, 0, 0, 0);
        float e0 = exp2_raw(EXS * c[0]);
        float e1 = exp2_raw(EXS * c[1]);
        float e2 = exp2_raw(EXS * c[2]);
        float e3 = exp2_raw(EXS * c[3]);
        sa[s] += (e0 + e1) + (e2 + e3);          // all for the same i
        *(int*)&buf[w][s][dl][boff] = pk4_fp8(e0, e1, e2, e3);
      }
    }
#pragma unroll
    for (int s = 0; s < 4; s++) {
      uint4 v = *(const uint4*)&buf[w][s][L][0];
      *(uint4*)(abase + (size_t)s*32768 + (size_t)(w*8 + g)*1024 + (size_t)L*16) = v;
    }
  }
#pragma unroll
  for (int s = 0; s < 4; s++) {
    float v = sa[s];
    v += __shfl_xor(v, 16); v += __shfl_xor(v, 32);
    if (quad == 0) reds[w][s][l15] = v;
  }
  __syncthreads();
  if (t < 64)
    rowsum[(size_t)bh_local*SEQ + i0blk + t] =
        (reds[0][t >> 4][t & 15] + reds[1][t >> 4][t & 15]) +
        (reds[2][t >> 4][t & 15] + reds[3][t >> 4][t & 15]);
}

__global__ void k_zero(float* __restrict__ o, int n) {
  int i = blockIdx.x*256 + threadIdx.x; if (i < n) o[i] = 0.f;
}

// ---------------- step-0 shortcut: m1 = mag(xf + m0v) -> frag-tiled fp8 ----------------
__global__ __launch_bounds__(256) void k_step0(const float* __restrict__ xf, u8* __restrict__ mT,
                                               float m0v) {
  __shared__ __align__(16) u8 tile_t[64][72];   // [d][i_local], +8 pad
  int bh = blockIdx.x >> 5;       // 32 i-tiles per bh
  int kt2 = blockIdx.x & 31;
  int i0 = kt2 * 64;
  int b = bh >> 4, h = bh & (HEADS-1);
  int t = threadIdx.x;
  int row = t >> 2, part = t & 3;            // i-row in tile, 16-float d-part
  const float* xr = xf + ((size_t)b*SEQ + i0 + row)*NDIM + h*DH + part*16;
  float v[16]; float s = 0.f;
#pragma unroll
  for (int e = 0; e < 16; e++) { float u = xr[e] + m0v; v[e] = u; s += u*u; }
  s += __shfl_xor(s, 1); s += __shfl_xor(s, 2);
  float t2 = 0.5f*(1.0f + sqrtf(1.0f + s * INV_SCALE2));
  float inv = 1.0f/(2.0f*t2);
#pragma unroll
  for (int e = 0; e < 16; e += 4) {
    int p = pk4_fp8(v[e]*inv, v[e+1]*inv, v[e+2]*inv, v[e+3]*inv);
    tile_t[part*16 + e + 0][row] = (u8)(p & 255);
    tile_t[part*16 + e + 1][row] = (u8)((p >> 8) & 255);
    tile_t[part*16 + e + 2][row] = (u8)((p >> 16) & 255);
    tile_t[part*16 + e + 3][row] = (u8)((p >> 24) & 255);
  }
  __syncthreads();
  int nt = t >> 6, Lw = t & 63;
  i64 lo = *(const i64*)&tile_t[nt*16 + (Lw & 15)][(Lw >> 4)*8];
  i64 hi = *(const i64*)&tile_t[nt*16 + (Lw & 15)][32 + (Lw >> 4)*8];
  u8* dst = mT + ((size_t)bh << 17) + ((size_t)(nt*32 + kt2)*64 + Lw)*16;
  *(i64*)dst = lo;
  *(i64*)(dst + 8) = hi;
}

// ---------------- fp8 MFMA mean-field step: NO LDS + XCD-affinity remap (R12 best) ----
template<int LAST>
__global__ __launch_bounds__(256) void k_step(const u8* __restrict__ attn, const u8* __restrict__ mT_in,
                                              const float* __restrict__ xf,
                                              const float* __restrict__ rowsum,
                                              u8* __restrict__ mT_out,
                                              float* __restrict__ out, int bh0, int CH) {
  int t = threadIdx.x;
  int w = t >> 6, L = t & 63;
  int quad = L >> 4, l15 = L & 15;
  int blk = blockIdx.x;
  int bh_local, I4;
  if (CH >= 8) {
    int gpb = CH >> 3;               // bh-groups per XCD
    int q = blk >> 3;
    bh_local = (blk & 7) + 8 * (q % gpb);   // blk%8 == bh_local%8 == XCD
    I4 = q / gpb;
  } else {
    bh_local = blk >> 5;
    I4 = blk & 31;
  }
  int bh = bh0 + bh_local;
  int I = I4*4 + w;                  // i-tile [0,128)
  int b = bh >> 4, hh = bh & (HEADS-1);
  const u8* ab = attn + ((size_t)bh_local << 22) + (size_t)I*32768 + (size_t)L*16;
  const u8* bb = mT_in + ((size_t)bh << 17) + (size_t)L*16;
  floatx4 acc[4];
#pragma unroll
  for (int j = 0; j < 4; j++) acc[j] = (floatx4){0.f,0.f,0.f,0.f};

#pragma unroll 4
  for (int kt2 = 0; kt2 < 32; kt2++) {
    i64x2 a  = *(const i64x2*)(ab + (size_t)kt2*1024);
    i64x2 b0 = *(const i64x2*)(bb + (size_t)kt2*1024);
    i64x2 b1 = *(const i64x2*)(bb + (size_t)(32 + kt2)*1024);
    i64x2 b2 = *(const i64x2*)(bb + (size_t)(64 + kt2)*1024);
    i64x2 b3 = *(const i64x2*)(bb + (size_t)(96 + kt2)*1024);
    acc[0] = __builtin_amdgcn_mfma_f32_16x16x32_fp8_fp8(a.x, b0.x, acc[0], 0, 0, 0);
    acc[1] = __builtin_amdgcn_mfma_f32_16x16x32_fp8_fp8(a.x, b1.x, acc[1], 0, 0, 0);
    acc[2] = __builtin_amdgcn_mfma_f32_16x16x32_fp8_fp8(a.x, b2.x, acc[2], 0, 0, 0);
    acc[3] = __builtin_amdgcn_mfma_f32_16x16x32_fp8_fp8(a.x, b3.x, acc[3], 0, 0, 0);
    acc[0] = __builtin_amdgcn_mfma_f32_16x16x32_fp8_fp8(a.y, b0.y, acc[0], 0, 0, 0);
    acc[1] = __builtin_amdgcn_mfma_f32_16x16x32_fp8_fp8(a.y, b1.y, acc[1], 0, 0, 0);
    acc[2] = __builtin_amdgcn_mfma_f32_16x16x32_fp8_fp8(a.y, b2.y, acc[2], 0, 0, 0);
    acc[3] = __builtin_amdgcn_mfma_f32_16x16x32_fp8_fp8(a.y, b3.y, acc[3], 0, 0, 0);
  }
  int ibase = I*16 + quad*4;
  float th[4][4]; float invr[4];
#pragma unroll
  for (int reg = 0; reg < 4; reg++) {
    float sinv = 1.0f / rowsum[(size_t)bh_local*SEQ + ibase + reg];
    size_t xoff = ((size_t)b*SEQ + ibase + reg)*NDIM + hh*DH + l15;
    float s = 0.f;
#pragma unroll
    for (int nt = 0; nt < 4; nt++) {
      float v = acc[nt][reg]*sinv + xf[xoff + nt*16];
      th[nt][reg] = v; s += v*v;
    }
    s += __shfl_xor(s, 1); s += __shfl_xor(s, 2); s += __shfl_xor(s, 4); s += __shfl_xor(s, 8);
    float tt2 = 0.5f*(1.0f + sqrtf(1.0f + s * INV_SCALE2));
    invr[reg] = 1.0f/(2.0f*tt2);
  }
  if (LAST) {
#pragma unroll
    for (int reg = 0; reg < 4; reg++) {
      size_t ooff = ((size_t)b*SEQ + ibase + reg)*NDIM + hh*DH + l15;
#pragma unroll
      for (int nt = 0; nt < 4; nt++) out[ooff + nt*16] = th[nt][reg]*invr[reg];
    }
  } else {
    int kt2o = I >> 2;
    int hf = (I >> 1) & 1;
    int lhi = ((I & 1)*2 + (quad >> 1)) & 3;
    u8* ob = mT_out + ((size_t)bh << 17) + (size_t)(lhi*16 + l15)*16 + hf*8 + (quad & 1)*4;
#pragma unroll
    for (int nt = 0; nt < 4; nt++) {
      int p = pk4_fp8(th[nt][0]*invr[0], th[nt][1]*invr[1],
                      th[nt][2]*invr[2], th[nt][3]*invr[3]);
      *(int*)(ob + (size_t)(nt*32 + kt2o)*1024) = p;
    }
  }
}

extern "C" void kernel_launch(void* const* d_in, const int* in_sizes, int n_in,
                              void* d_out, int out_size, void* d_ws, size_t ws_size,
                              hipStream_t stream) {
  const void* x    = d_in[0];
  const void* w_qk = d_in[1];
  const void* w1   = d_in[2];
  const void* w2   = d_in[3];
  float* out = (float*)d_out;

  const size_t E = (size_t)BQ*SEQ*NDIM;     // 4,194,304
  const int NW_QK = 2*NDIM*NDIM;
  const int NW1   = 4*NDIM*NDIM;
  const int NW2   = 4*NDIM*NDIM;

  char* ws = (char*)d_ws;
  size_t off = 0;
  auto alloc = [&](size_t bytes) { void* p = ws + off; off += (bytes + 255) & ~255ull; return p; };
  int*  flag = (int*)alloc(256);
  u16*  xs  = (u16*)alloc(E*2);             // scaled-normalized x (bf16)
  u16*  qb  = (u16*)alloc(E*2);             // q normalized [B,H,N,DH] bf16
  u16*  kb  = (u16*)alloc(E*2);
  float* xf = (float*)alloc(E*4);           // external field fp32
  u8*   mT  = (u8*)alloc(E*2);              // two fp8 m-buffers, frag-tiled
  float* rsum = (float*)alloc((size_t)BQ*HEADS*SEQ*4);  // softmax denominators (chunk-local)
  u8*   mTa = mT;
  u8*   mTb = mT + E;

  char* S = ws + off;
  size_t availS = (ws_size > off) ? ws_size - off : 0;
  // S-region temporal plan: [wqkb|qkraw] -> [.|.|w1b|w2b|hbuf|pbuf] -> [attn chunk fp8]
  u16* wqkb  = (u16*)(S);
  u16* qkraw = (u16*)(S + 4194304);
  u16* w1b   = (u16*)(S + 20971520);
  u16* w2b   = (u16*)(S + 29360128);
  u16* hbuf  = (u16*)(S + 37748736);
  u8*  attn  = (u8*)(S);
  u16* xb    = (u16*)mT;                     // alias (2E bytes): dead before k_step0

  const int rcs[6] = {4096, 2048, 1024, 512, 256, 128};
  int RC = 0;
  for (int i = 0; i < 6; i++)
    if (37748736ull + (size_t)rcs[i]*4096*2 <= availS) { RC = rcs[i]; break; }
  const int chs[6] = {32, 16, 8, 4, 2, 1};
  int CH = 0;
  for (int i = 0; i < 6; i++)
    if ((size_t)chs[i]*SEQ*SEQ <= availS) { CH = chs[i]; break; }
  if (RC == 0 || CH == 0) {
    k_zero<<<(out_size+255)/256, 256, 0, stream>>>(out, out_size);
    return;
  }
  // split-K partial buffer (2 x RC x NDIM fp32) after hbuf; fallback if it doesn't fit
  size_t pboff = 37748736ull + (size_t)RC*4096*2;
  int use_ksp = (pboff + (size_t)RC*NDIM*8 <= availS) ? 1 : 0;
  float* pbuf = (float*)(S + pboff);

  const int M = BQ*SEQ;  // 4096

  // dtype probe + canonical bf16 conversion
  k_flag0<<<1, 64, 0, stream>>>(flag);
  k_probe<<<256, 256, 0, stream>>>((const u16*)x, flag);
  k_convert<<<(int)(E/256), 256, 0, stream>>>(x, xb, flag, (int)E);
  k_convert<<<NW_QK/256, 256, 0, stream>>>(w_qk, wqkb, flag, NW_QK);
  k_convert<<<NW1/256, 256, 0, stream>>>(w1, w1b, flag, NW1);
  k_convert<<<NW2/256, 256, 0, stream>>>(w2, w2b, flag, NW2);

  k_norm_scale<<<M, 256, 0, stream>>>(xb, xs);
  { dim3 g(M/128, 2048/128); k_gemm<1,0,0><<<g, 256, 0, stream>>>(xs, wqkb, nullptr, qkraw, nullptr, M, 2048, 1024); }
  k_headnorm<<<M*HEADS, 64, 0, stream>>>(qkraw, qb, kb);

  for (int c = 0; c < M/RC; c++) {
    const u16* xsc = xs + (size_t)c*RC*NDIM;
    { dim3 g(RC/128, 4096/128); k_gemm<1,1,0><<<g, 256, 0, stream>>>(xsc, w1b, nullptr, hbuf, nullptr, RC, 4096, 1024); }
    if (use_ksp) {
      dim3 g(RC/128, 1024/128, 2);
      k_gemm_w2ks<<<g, 512, 0, stream>>>(hbuf, w2b, pbuf, RC, 1024, 4096);
      int n = RC*NDIM;
      k_w2red<<<n/1024, 256, 0, stream>>>(pbuf, pbuf + n, xsc, xf + (size_t)c*RC*NDIM, n);
    } else {
      dim3 g(RC/128, 1024/128);
      k_gemm_w2<<<g, 512, 0, stream>>>(hbuf, w2b, xf + (size_t)c*RC*NDIM, xsc, RC, 1024, 4096);
    }
  }

  // step 0 closed form: m1 = mag(xf + m0v) since normalized attn rows sum to 1 and m0 is constant
  float t0 = 0.5f*(1.0f + sqrtf(1.0f + 64.0f/511.0f));
  float m0v = 1.0f/(2.0f*t0);
  k_step0<<<BQ*HEADS*32, 256, 0, stream>>>(xf, mTa, m0v);

  for (int c0 = 0; c0 < BQ*HEADS; c0 += CH) {
    k_attn<<<CH*32, 256, 0, stream>>>(qb, kb, attn, rsum, c0, CH);
    for (int s = 1; s < NSTEPS; s++) {
      u8* src = (s & 1) ? mTa : mTb;
      u8* dst = (s & 1) ? mTb : mTa;
      if (s == NSTEPS-1)
        k_step<1><<<CH*32, 256, 0, stream>>>(attn, src, xf, rsum, nullptr, out, c0, CH);
      else
        k_step<0><<<CH*32, 256, 0, stream>>>(attn, src, xf, rsum, dst, nullptr, c0, CH);
    }
  }
}

// Round 15
// 515.460 us; speedup vs baseline: 3.4068x; 1.0064x over previous
//
#include <hip/hip_runtime.h>
#include <hip/hip_bf16.h>
#include <math.h>

#define BQ 2
#define SEQ 2048
#define NDIM 1024
#define HEADS 16
#define DH 64
#define NSTEPS 8
#define SCALE 22.60530911f      /* sqrt(511) */
#define SCALE_HEAD 5.567764363f /* sqrt(31)  */
#define INV_SCALE2 (1.0f/511.0f)
#define EXS 8.0325527f          /* SCALE_HEAD * log2(e) */

typedef unsigned short u16;
typedef unsigned char u8;
typedef long long i64;
typedef __attribute__((ext_vector_type(8))) short bf16x8;   // 8 bf16 = 4 VGPR
typedef __attribute__((ext_vector_type(4))) float floatx4;  // MFMA 16x16 acc
typedef __attribute__((ext_vector_type(2))) long long i64x2; // 16B = two fp8 K=32 frags

__device__ __forceinline__ float bf2f(u16 u) {
  union { unsigned int i; float f; } v; v.i = ((unsigned int)u) << 16; return v.f;
}
__device__ __forceinline__ u16 f2bf(float f) {
  union { float f; unsigned int i; } v; v.f = f;
  unsigned int x = v.i;
  return (u16)((x + 0x7fffu + ((x >> 16) & 1u)) >> 16);
}
// raw v_exp_f32 via compiler-modeled builtin (inputs bounded here)
#if __has_builtin(__builtin_amdgcn_exp2f)
__device__ __forceinline__ float exp2_raw(float x) { return __builtin_amdgcn_exp2f(x); }
#else
__device__ __forceinline__ float exp2_raw(float x) { return exp2f(x); }
#endif
#if __has_builtin(__builtin_amdgcn_rcpf)
__device__ __forceinline__ float rcp_raw(float x) { return __builtin_amdgcn_rcpf(x); }
#else
__device__ __forceinline__ float rcp_raw(float x) { return 1.0f/x; }
#endif

// tanh-approx GELU: max |diff vs exact| ~5e-4, below bf16 output quantization.
__device__ __forceinline__ float gelu_tanh(float v) {
  float v2 = v*v;
  float u = v * __builtin_fmaf(0.0356774081f, v2, 0.7978845608f);
  float t = exp2_raw(2.8853900817779268f * u);   // e^{2u}, u in [-5.6, 5.6]
  float th = (t - 1.0f) * rcp_raw(t + 1.0f);
  return 0.5f * v * (1.0f + th);
}

// packed fp8 conversion via HW cvt (gfx950 native fp8 = OCP e4m3fn)
__device__ __forceinline__ int pk4_fp8(float a, float b, float c, float d) {
  int p = 0;
  p = __builtin_amdgcn_cvt_pk_fp8_f32(a, b, p, false);
  p = __builtin_amdgcn_cvt_pk_fp8_f32(c, d, p, true);
  return p;
}

// async global->LDS, 16B per lane; LDS dest = wave-uniform base + lane*16
#define GLD16(gp, lp) __builtin_amdgcn_global_load_lds( \
    (__attribute__((address_space(1))) void*)(gp),      \
    (__attribute__((address_space(3))) void*)(lp), 16, 0, 0)

/* ===================== FRAG-TILED OPERAND LAYOUTS =====================
 * A (attn, per bh_local, 4MB): element e_raw[i][j]:
 *   I=i>>4, kt2=j>>6, hf=(j>>5)&1, Lhi=(j>>3)&3, e=j&7, l15=i&15
 *   addr = ((I*32 + kt2)*64 + Lhi*16 + l15)*16 + hf*8 + e
 * B (m, per bh, 128KB): element m[d][j]:
 *   nt=d>>4, l15=d&15, kt2=j>>6, hf=(j>>5)&1, Lhi=(j>>3)&3, e=j&7
 *   addr = ((nt*32 + kt2)*64 + Lhi*16 + l15)*16 + hf*8 + e
 * Lane L of an MFMA then loads its frag as one dwordx4 at base + L*16. */

// ---------------- dtype probe: flag=1 if input is fp32 ----------------
__global__ void k_flag0(int* flag) { if (threadIdx.x == 0 && blockIdx.x == 0) *flag = 0; }

__global__ __launch_bounds__(256) void k_probe(const u16* __restrict__ x, int* __restrict__ flag) {
  int i = blockIdx.x * 256 + threadIdx.x;
  float v = bf2f(x[i]);
  if (!(fabsf(v) <= 1e4f)) atomicOr(flag, 1);
}

__global__ __launch_bounds__(256) void k_convert(const void* __restrict__ in, u16* __restrict__ outb,
                                                 const int* __restrict__ flag, int n) {
  int i = blockIdx.x * 256 + threadIdx.x;
  if (i >= n) return;
  if (*flag) outb[i] = f2bf(((const float*)in)[i]);
  else       outb[i] = ((const u16*)in)[i];
}

// ---------------- normalize + scale x -> xs (bf16) ----------------
__global__ __launch_bounds__(256) void k_norm_scale(const u16* __restrict__ x, u16* __restrict__ xs) {
  __shared__ float red[256];
  int row = blockIdx.x;
  const u16* xr = x + (size_t)row * NDIM;
  u16* orow = xs + (size_t)row * NDIM;
  int t = threadIdx.x;
  float vals[4]; float s = 0.f;
#pragma unroll
  for (int e = 0; e < 4; e++) { float v = bf2f(xr[t + 256*e]); vals[e] = v; s += v*v; }
  red[t] = s; __syncthreads();
  for (int o = 128; o > 0; o >>= 1) { if (t < o) red[t] += red[t+o]; __syncthreads(); }
  float sc = SCALE / fmaxf(sqrtf(red[0]), 1e-12f);
#pragma unroll
  for (int e = 0; e < 4; e++) orow[t + 256*e] = f2bf(vals[e] * sc);
}

// ---------------- MFMA GEMM (bf16), BK=64 via dual 32-col slabs ----------------
template<int OUT_BF16, int GELU, int ADDSRC>
__global__ __launch_bounds__(256) void k_gemm(const u16* __restrict__ A, const u16* __restrict__ W,
                                              float* __restrict__ Cf, u16* __restrict__ Cb,
                                              const u16* __restrict__ addsrc, int M, int N, int K) {
  __shared__ __align__(16) u16 As[2][128*32];
  __shared__ __align__(16) u16 Bs[2][128*32];
  int t = threadIdx.x;
  int w = t >> 6, L = t & 63;
  int quad = L >> 4, l15 = L & 15;
  int wr = w >> 1, wc = w & 1;
  int bm = blockIdx.x * 128, bn = blockIdx.y * 128;
  int srow = L >> 2, scol = (L & 3) * 8;
  floatx4 acc[4][4];
#pragma unroll
  for (int i = 0; i < 4; i++)
#pragma unroll
    for (int j = 0; j < 4; j++) acc[i][j] = (floatx4){0.f,0.f,0.f,0.f};

  for (int k0 = 0; k0 < K; k0 += 64) {
#pragma unroll
    for (int c = 0; c < 2; c++) {
      int r = c*64 + w*16 + srow;
      const u16* ap = A + (size_t)(bm + r)*K + k0 + scol;
      const u16* wp = W + (size_t)(bn + r)*K + k0 + scol;
      GLD16(ap,      &As[0][(c*64 + w*16)*32]);
      GLD16(ap + 32, &As[1][(c*64 + w*16)*32]);
      GLD16(wp,      &Bs[0][(c*64 + w*16)*32]);
      GLD16(wp + 32, &Bs[1][(c*64 + w*16)*32]);
    }
    __syncthreads();
#pragma unroll
    for (int s = 0; s < 2; s++) {
      bf16x8 af[4], bfr[4];
#pragma unroll
      for (int mt = 0; mt < 4; mt++) af[mt]  = *(const bf16x8*)&As[s][(wr*64 + mt*16 + l15)*32 + quad*8];
#pragma unroll
      for (int nt = 0; nt < 4; nt++) bfr[nt] = *(const bf16x8*)&Bs[s][(wc*64 + nt*16 + l15)*32 + quad*8];
#pragma unroll
      for (int mt = 0; mt < 4; mt++)
#pragma unroll
        for (int nt = 0; nt < 4; nt++)
          acc[mt][nt] = __builtin_amdgcn_mfma_f32_16x16x32_bf16(af[mt], bfr[nt], acc[mt][nt], 0, 0, 0);
    }
    __syncthreads();
  }
#pragma unroll
  for (int mt = 0; mt < 4; mt++)
#pragma unroll
    for (int reg = 0; reg < 4; reg++) {
      int m = bm + wr*64 + mt*16 + quad*4 + reg;
      size_t rowoff = (size_t)m * N;
#pragma unroll
      for (int nt = 0; nt < 4; nt++) {
        int n = bn + wc*64 + nt*16 + l15;
        float v = acc[mt][nt][reg];
        if (GELU) v = gelu_tanh(v);
        if (ADDSRC) v += bf2f(addsrc[rowoff + n]);
        if (OUT_BF16) Cb[rowoff + n] = f2bf(v);
        else Cf[rowoff + n] = v;
      }
    }
}

// ---------------- w2 GEMM fallback: intra-block split-K only (1 block/CU) ----------
__global__ __launch_bounds__(512) void k_gemm_w2(const u16* __restrict__ A, const u16* __restrict__ W,
                                                 float* __restrict__ Cf,
                                                 const u16* __restrict__ addsrc, int M, int N, int K) {
  __shared__ __align__(16) u16 As[2][128*32];
  __shared__ __align__(16) u16 Bs[2][128*32];
  int t = threadIdx.x;
  int g = t >> 8;
  int tg = t & 255;
  int w = tg >> 6;
  int L = t & 63;
  int quad = L >> 4, l15 = L & 15;
  int wr = w >> 1, wc = w & 1;
  int bm = blockIdx.x * 128, bn = blockIdx.y * 128;
  int srow = L >> 2, scol = (L & 3) * 8;
  int kg0 = g * (K >> 1);
  floatx4 acc[4][4];
#pragma unroll
  for (int i = 0; i < 4; i++)
#pragma unroll
    for (int j = 0; j < 4; j++) acc[i][j] = (floatx4){0.f,0.f,0.f,0.f};

  for (int k0 = 0; k0 < (K >> 1); k0 += 32) {
    int kk = kg0 + k0;
#pragma unroll
    for (int c = 0; c < 2; c++) {
      int r = c*64 + w*16 + srow;
      GLD16(A + (size_t)(bm + r)*K + kk + scol, &As[g][(c*64 + w*16)*32]);
      GLD16(W + (size_t)(bn + r)*K + kk + scol, &Bs[g][(c*64 + w*16)*32]);
    }
    __syncthreads();
    bf16x8 af[4], bfr[4];
#pragma unroll
    for (int mt = 0; mt < 4; mt++) af[mt]  = *(const bf16x8*)&As[g][(wr*64 + mt*16 + l15)*32 + quad*8];
#pragma unroll
    for (int nt = 0; nt < 4; nt++) bfr[nt] = *(const bf16x8*)&Bs[g][(wc*64 + nt*16 + l15)*32 + quad*8];
#pragma unroll
    for (int mt = 0; mt < 4; mt++)
#pragma unroll
      for (int nt = 0; nt < 4; nt++)
        acc[mt][nt] = __builtin_amdgcn_mfma_f32_16x16x32_bf16(af[mt], bfr[nt], acc[mt][nt], 0, 0, 0);
    __syncthreads();
  }
  float* LFA = (float*)&As[0][0];
  float* LFB = (float*)&Bs[0][0];
#pragma unroll
  for (int r = 0; r < 2; r++) {
    float* myW = g ? LFA : LFB;
    int mtW = g ? r : (2 + r);
#pragma unroll
    for (int reg = 0; reg < 4; reg++)
#pragma unroll
      for (int nt = 0; nt < 4; nt++)
        myW[(wr*16 + quad*4 + reg)*128 + wc*64 + nt*16 + l15] = acc[mtW][nt][reg];
    __syncthreads();
    float* myR = g ? LFB : LFA;
    int mtS = g ? (2 + r) : r;
#pragma unroll
    for (int reg = 0; reg < 4; reg++) {
      int m = bm + wr*64 + mtS*16 + quad*4 + reg;
      size_t rowoff = (size_t)m * N;
#pragma unroll
      for (int nt = 0; nt < 4; nt++) {
        int n = bn + wc*64 + nt*16 + l15;
        float v = acc[mtS][nt][reg] + myR[(wr*16 + quad*4 + reg)*128 + wc*64 + nt*16 + l15];
        v += bf2f(addsrc[rowoff + n]);
        Cf[rowoff + n] = v;
      }
    }
    __syncthreads();
  }
}

// ---------------- w2 GEMM: inter-block (z=2) + intra-block (g=2) split-K ----------
__global__ __launch_bounds__(512) void k_gemm_w2ks(const u16* __restrict__ A, const u16* __restrict__ W,
                                                   float* __restrict__ pbuf, int M, int N, int K) {
  __shared__ __align__(16) u16 As[2][128*32];
  __shared__ __align__(16) u16 Bs[2][128*32];
  int t = threadIdx.x;
  int g = t >> 8;                 // K-quarter group within block (wave-uniform)
  int tg = t & 255;
  int w = tg >> 6;
  int L = t & 63;
  int quad = L >> 4, l15 = L & 15;
  int wr = w >> 1, wc = w & 1;
  int bm = blockIdx.x * 128, bn = blockIdx.y * 128;
  int z = blockIdx.z;             // K-half
  int srow = L >> 2, scol = (L & 3) * 8;
  int kg0 = z * (K >> 1) + g * (K >> 2);
  floatx4 acc[4][4];
#pragma unroll
  for (int i = 0; i < 4; i++)
#pragma unroll
    for (int j = 0; j < 4; j++) acc[i][j] = (floatx4){0.f,0.f,0.f,0.f};

  for (int k0 = 0; k0 < (K >> 2); k0 += 32) {
    int kk = kg0 + k0;
#pragma unroll
    for (int c = 0; c < 2; c++) {
      int r = c*64 + w*16 + srow;
      GLD16(A + (size_t)(bm + r)*K + kk + scol, &As[g][(c*64 + w*16)*32]);
      GLD16(W + (size_t)(bn + r)*K + kk + scol, &Bs[g][(c*64 + w*16)*32]);
    }
    __syncthreads();
    bf16x8 af[4], bfr[4];
#pragma unroll
    for (int mt = 0; mt < 4; mt++) af[mt]  = *(const bf16x8*)&As[g][(wr*64 + mt*16 + l15)*32 + quad*8];
#pragma unroll
    for (int nt = 0; nt < 4; nt++) bfr[nt] = *(const bf16x8*)&Bs[g][(wc*64 + nt*16 + l15)*32 + quad*8];
#pragma unroll
    for (int mt = 0; mt < 4; mt++)
#pragma unroll
      for (int nt = 0; nt < 4; nt++)
        acc[mt][nt] = __builtin_amdgcn_mfma_f32_16x16x32_bf16(af[mt], bfr[nt], acc[mt][nt], 0, 0, 0);
    __syncthreads();
  }
  float* LFA = (float*)&As[0][0];
  float* LFB = (float*)&Bs[0][0];
  float* pb = pbuf + (size_t)z * M * N;
#pragma unroll
  for (int r = 0; r < 2; r++) {
    float* myW = g ? LFA : LFB;
    int mtW = g ? r : (2 + r);
#pragma unroll
    for (int reg = 0; reg < 4; reg++)
#pragma unroll
      for (int nt = 0; nt < 4; nt++)
        myW[(wr*16 + quad*4 + reg)*128 + wc*64 + nt*16 + l15] = acc[mtW][nt][reg];
    __syncthreads();
    float* myR = g ? LFB : LFA;
    int mtS = g ? (2 + r) : r;
#pragma unroll
    for (int reg = 0; reg < 4; reg++) {
      int m = bm + wr*64 + mtS*16 + quad*4 + reg;
      size_t rowoff = (size_t)m * N;
#pragma unroll
      for (int nt = 0; nt < 4; nt++) {
        int n = bn + wc*64 + nt*16 + l15;
        pb[rowoff + n] = acc[mtS][nt][reg] + myR[(wr*16 + quad*4 + reg)*128 + wc*64 + nt*16 + l15];
      }
    }
    __syncthreads();
  }
}

// reduce: xf = p0 + p1 + bf16(xs); vectorized x4
__global__ __launch_bounds__(256) void k_w2red(const float* __restrict__ p0, const float* __restrict__ p1,
                                               const u16* __restrict__ xs, float* __restrict__ xf, int n) {
  int i = (blockIdx.x * 256 + threadIdx.x) * 4;
  if (i >= n) return;
  float4 a = *(const float4*)(p0 + i);
  float4 b = *(const float4*)(p1 + i);
  ushort4 s = *(const ushort4*)(xs + i);
  float4 o;
  o.x = a.x + b.x + bf2f(s.x);
  o.y = a.y + b.y + bf2f(s.y);
  o.z = a.z + b.z + bf2f(s.z);
  o.w = a.w + b.w + bf2f(s.w);
  *(float4*)(xf + i) = o;
}

// ---------------- per-head normalize q,k -> [B,H,N,DH] bf16 ----------------
__global__ __launch_bounds__(64) void k_headnorm(const u16* __restrict__ qkraw,
                                                 u16* __restrict__ qn, u16* __restrict__ kn) {
  int blk = blockIdx.x;
  int h = blk & (HEADS-1); int bi = blk >> 4;
  int b = bi >> 11, i = bi & (SEQ-1);
  int d = threadIdx.x;
  const u16* base = qkraw + (size_t)bi * (2*NDIM);
  float qv = bf2f(base[h*DH + d]);
  float kv = bf2f(base[NDIM + h*DH + d]);
  float qs = qv*qv, ks = kv*kv;
#pragma unroll
  for (int o = 32; o > 0; o >>= 1) { qs += __shfl_xor(qs, o); ks += __shfl_xor(ks, o); }
  size_t oidx = ((size_t)(b*HEADS + h) * SEQ + i) * DH + d;
  qn[oidx] = f2bf(qv / fmaxf(sqrtf(qs), 1e-12f));
  kn[oidx] = f2bf(kv / fmaxf(sqrtf(ks), 1e-12f));
}

// ---------------- MFMA attn: 64 i-rows per wave + XCD affinity + T5 setprio ----------
// No inner barriers -> independent waves at different phases: the T5-positive regime
// (guide m191: +4-7% attn). MFMA cluster per j-tile wrapped in setprio(1)/(0).
__global__ __launch_bounds__(256, 4) void k_attn(const u16* __restrict__ qb, const u16* __restrict__ kb,
                                                 u8* __restrict__ attn, float* __restrict__ rowsum,
                                                 int bh0, int CH) {
  __shared__ __align__(16) u8 buf[4][4][64][16];   // [wave][i-subtile][row][16B]
  __shared__ float reds[4][4][16];                 // [wave][i-subtile][l15]
  int t = threadIdx.x;
  int w = t >> 6, L = t & 63;
  int quad = L >> 4, l15 = L & 15;
  int blk = blockIdx.x;
  int bh_local, islice;
  if (CH >= 8) {
    int gpb = CH >> 3;                             // bh-groups per XCD
    int q = blk >> 3;
    bh_local = (blk & 7) + 8 * (q % gpb);          // blk%8 == bh_local%8 == XCD
    islice = q / gpb;                              // [0,32)
  } else {
    bh_local = blk >> 5;
    islice = blk & 31;
  }
  int bh = bh0 + bh_local;
  int i0blk = islice * 64;
  bf16x8 q0[4], q1[4];
#pragma unroll
  for (int s = 0; s < 4; s++) {
    const u16* qrow = qb + ((size_t)bh*SEQ + i0blk + s*16 + l15)*DH + quad*8;
    q0[s] = *(const bf16x8*)qrow;
    q1[s] = *(const bf16x8*)(qrow + 32);
  }
  const u16* kbase = kb + (size_t)bh*SEQ*DH;
  u8* abase = attn + ((size_t)bh_local << 22) + (size_t)(i0blk >> 4)*32768;
  float sa[4] = {0.f, 0.f, 0.f, 0.f};
  for (int g = 0; g < 8; g++) {
#pragma unroll 2
    for (int tt4 = 0; tt4 < 4; tt4++) {
      int j = w*512 + (g*4 + tt4)*16 + l15;
      const u16* krow = kbase + (size_t)j*DH + quad*8;
      bf16x8 a0 = *(const bf16x8*)krow;
      bf16x8 a1 = *(const bf16x8*)(krow + 32);
      int dl = ((tt4*2 + (quad>>1)) & 3)*16 + l15;
      int boff = (tt4>>1)*8 + (quad&1)*4;
      floatx4 cs[4];
      __builtin_amdgcn_s_setprio(1);
#pragma unroll
      for (int s = 0; s < 4; s++) {
        floatx4 c = (floatx4){0.f,0.f,0.f,0.f};
        c = __builtin_amdgcn_mfma_f32_16x16x32_bf16(a0, q0[s], c, 0, 0, 0);
        cs[s] = __builtin_amdgcn_mfma_f32_16x16x32_bf16(a1, q1[s], c, 0, 0, 0);
      }
      __builtin_amdgcn_s_setprio(0);
#pragma unroll
      for (int s = 0; s < 4; s++) {
        float e0 = exp2_raw(EXS * cs[s][0]);
        float e1 = exp2_raw(EXS * cs[s][1]);
        float e2 = exp2_raw(EXS * cs[s][2]);
        float e3 = exp2_raw(EXS * cs[s][3]);
        sa[s] += (e0 + e1) + (e2 + e3);          // all for the same i
        *(int*)&buf[w][s][dl][boff] = pk4_fp8(e0, e1, e2, e3);
      }
    }
#pragma unroll
    for (int s = 0; s < 4; s++) {
      uint4 v = *(const uint4*)&buf[w][s][L][0];
      *(uint4*)(abase + (size_t)s*32768 + (size_t)(w*8 + g)*1024 + (size_t)L*16) = v;
    }
  }
#pragma unroll
  for (int s = 0; s < 4; s++) {
    float v = sa[s];
    v += __shfl_xor(v, 16); v += __shfl_xor(v, 32);
    if (quad == 0) reds[w][s][l15] = v;
  }
  __syncthreads();
  if (t < 64)
    rowsum[(size_t)bh_local*SEQ + i0blk + t] =
        (reds[0][t >> 4][t & 15] + reds[1][t >> 4][t & 15]) +
        (reds[2][t >> 4][t & 15] + reds[3][t >> 4][t & 15]);
}

__global__ void k_zero(float* __restrict__ o, int n) {
  int i = blockIdx.x*256 + threadIdx.x; if (i < n) o[i] = 0.f;
}

// ---------------- step-0 shortcut: m1 = mag(xf + m0v) -> frag-tiled fp8 ----------------
__global__ __launch_bounds__(256) void k_step0(const float* __restrict__ xf, u8* __restrict__ mT,
                                               float m0v) {
  __shared__ __align__(16) u8 tile_t[64][72];   // [d][i_local], +8 pad
  int bh = blockIdx.x >> 5;       // 32 i-tiles per bh
  int kt2 = blockIdx.x & 31;
  int i0 = kt2 * 64;
  int b = bh >> 4, h = bh & (HEADS-1);
  int t = threadIdx.x;
  int row = t >> 2, part = t & 3;            // i-row in tile, 16-float d-part
  const float* xr = xf + ((size_t)b*SEQ + i0 + row)*NDIM + h*DH + part*16;
  float v[16]; float s = 0.f;
#pragma unroll
  for (int e = 0; e < 16; e++) { float u = xr[e] + m0v; v[e] = u; s += u*u; }
  s += __shfl_xor(s, 1); s += __shfl_xor(s, 2);
  float t2 = 0.5f*(1.0f + sqrtf(1.0f + s * INV_SCALE2));
  float inv = 1.0f/(2.0f*t2);
#pragma unroll
  for (int e = 0; e < 16; e += 4) {
    int p = pk4_fp8(v[e]*inv, v[e+1]*inv, v[e+2]*inv, v[e+3]*inv);
    tile_t[part*16 + e + 0][row] = (u8)(p & 255);
    tile_t[part*16 + e + 1][row] = (u8)((p >> 8) & 255);
    tile_t[part*16 + e + 2][row] = (u8)((p >> 16) & 255);
    tile_t[part*16 + e + 3][row] = (u8)((p >> 24) & 255);
  }
  __syncthreads();
  int nt = t >> 6, Lw = t & 63;
  i64 lo = *(const i64*)&tile_t[nt*16 + (Lw & 15)][(Lw >> 4)*8];
  i64 hi = *(const i64*)&tile_t[nt*16 + (Lw & 15)][32 + (Lw >> 4)*8];
  u8* dst = mT + ((size_t)bh << 17) + ((size_t)(nt*32 + kt2)*64 + Lw)*16;
  *(i64*)dst = lo;
  *(i64*)(dst + 8) = hi;
}

// ---------------- fp8 MFMA mean-field step: NO LDS + XCD affinity + T5 setprio ----
template<int LAST>
__global__ __launch_bounds__(256) void k_step(const u8* __restrict__ attn, const u8* __restrict__ mT_in,
                                              const float* __restrict__ xf,
                                              const float* __restrict__ rowsum,
                                              u8* __restrict__ mT_out,
                                              float* __restrict__ out, int bh0, int CH) {
  int t = threadIdx.x;
  int w = t >> 6, L = t & 63;
  int quad = L >> 4, l15 = L & 15;
  int blk = blockIdx.x;
  int bh_local, I4;
  if (CH >= 8) {
    int gpb = CH >> 3;               // bh-groups per XCD
    int q = blk >> 3;
    bh_local = (blk & 7) + 8 * (q % gpb);   // blk%8 == bh_local%8 == XCD
    I4 = q / gpb;
  } else {
    bh_local = blk >> 5;
    I4 = blk & 31;
  }
  int bh = bh0 + bh_local;
  int I = I4*4 + w;                  // i-tile [0,128)
  int b = bh >> 4, hh = bh & (HEADS-1);
  const u8* ab = attn + ((size_t)bh_local << 22) + (size_t)I*32768 + (size_t)L*16;
  const u8* bb = mT_in + ((size_t)bh << 17) + (size_t)L*16;
  floatx4 acc[4];
#pragma unroll
  for (int j = 0; j < 4; j++) acc[j] = (floatx4){0.f,0.f,0.f,0.f};

#pragma unroll 4
  for (int kt2 = 0; kt2 < 32; kt2++) {
    i64x2 a  = *(const i64x2*)(ab + (size_t)kt2*1024);
    i64x2 b0 = *(const i64x2*)(bb + (size_t)kt2*1024);
    i64x2 b1 = *(const i64x2*)(bb + (size_t)(32 + kt2)*1024);
    i64x2 b2 = *(const i64x2*)(bb + (size_t)(64 + kt2)*1024);
    i64x2 b3 = *(const i64x2*)(bb + (size_t)(96 + kt2)*1024);
    __builtin_amdgcn_s_setprio(1);
    acc[0] = __builtin_amdgcn_mfma_f32_16x16x32_fp8_fp8(a.x, b0.x, acc[0], 0, 0, 0);
    acc[1] = __builtin_amdgcn_mfma_f32_16x16x32_fp8_fp8(a.x, b1.x, acc[1], 0, 0, 0);
    acc[2] = __builtin_amdgcn_mfma_f32_16x16x32_fp8_fp8(a.x, b2.x, acc[2], 0, 0, 0);
    acc[3] = __builtin_amdgcn_mfma_f32_16x16x32_fp8_fp8(a.x, b3.x, acc[3], 0, 0, 0);
    acc[0] = __builtin_amdgcn_mfma_f32_16x16x32_fp8_fp8(a.y, b0.y, acc[0], 0, 0, 0);
    acc[1] = __builtin_amdgcn_mfma_f32_16x16x32_fp8_fp8(a.y, b1.y, acc[1], 0, 0, 0);
    acc[2] = __builtin_amdgcn_mfma_f32_16x16x32_fp8_fp8(a.y, b2.y, acc[2], 0, 0, 0);
    acc[3] = __builtin_amdgcn_mfma_f32_16x16x32_fp8_fp8(a.y, b3.y, acc[3], 0, 0, 0);
    __builtin_amdgcn_s_setprio(0);
  }
  int ibase = I*16 + quad*4;
  float th[4][4]; float invr[4];
#pragma unroll
  for (int reg = 0; reg < 4; reg++) {
    float sinv = 1.0f / rowsum[(size_t)bh_local*SEQ + ibase + reg];
    size_t xoff = ((size_t)b*SEQ + ibase + reg)*NDIM + hh*DH + l15;
    float s = 0.f;
#pragma unroll
    for (int nt = 0; nt < 4; nt++) {
      float v = acc[nt][reg]*sinv + xf[xoff + nt*16];
      th[nt][reg] = v; s += v*v;
    }
    s += __shfl_xor(s, 1); s += __shfl_xor(s, 2); s += __shfl_xor(s, 4); s += __shfl_xor(s, 8);
    float tt2 = 0.5f*(1.0f + sqrtf(1.0f + s * INV_SCALE2));
    invr[reg] = 1.0f/(2.0f*tt2);
  }
  if (LAST) {
#pragma unroll
    for (int reg = 0; reg < 4; reg++) {
      size_t ooff = ((size_t)b*SEQ + ibase + reg)*NDIM + hh*DH + l15;
#pragma unroll
      for (int nt = 0; nt < 4; nt++) out[ooff + nt*16] = th[nt][reg]*invr[reg];
    }
  } else {
    int kt2o = I >> 2;
    int hf = (I >> 1) & 1;
    int lhi = ((I & 1)*2 + (quad >> 1)) & 3;
    u8* ob = mT_out + ((size_t)bh << 17) + (size_t)(lhi*16 + l15)*16 + hf*8 + (quad & 1)*4;
#pragma unroll
    for (int nt = 0; nt < 4; nt++) {
      int p = pk4_fp8(th[nt][0]*invr[0], th[nt][1]*invr[1],
                      th[nt][2]*invr[2], th[nt][3]*invr[3]);
      *(int*)(ob + (size_t)(nt*32 + kt2o)*1024) = p;
    }
  }
}

extern "C" void kernel_launch(void* const* d_in, const int* in_sizes, int n_in,
                              void* d_out, int out_size, void* d_ws, size_t ws_size,
                              hipStream_t stream) {
  const void* x    = d_in[0];
  const void* w_qk = d_in[1];
  const void* w1   = d_in[2];
  const void* w2   = d_in[3];
  float* out = (float*)d_out;

  const size_t E = (size_t)BQ*SEQ*NDIM;     // 4,194,304
  const int NW_QK = 2*NDIM*NDIM;
  const int NW1   = 4*NDIM*NDIM;
  const int NW2   = 4*NDIM*NDIM;

  char* ws = (char*)d_ws;
  size_t off = 0;
  auto alloc = [&](size_t bytes) { void* p = ws + off; off += (bytes + 255) & ~255ull; return p; };
  int*  flag = (int*)alloc(256);
  u16*  xs  = (u16*)alloc(E*2);             // scaled-normalized x (bf16)
  u16*  qb  = (u16*)alloc(E*2);             // q normalized [B,H,N,DH] bf16
  u16*  kb  = (u16*)alloc(E*2);
  float* xf = (float*)alloc(E*4);           // external field fp32
  u8*   mT  = (u8*)alloc(E*2);              // two fp8 m-buffers, frag-tiled
  float* rsum = (float*)alloc((size_t)BQ*HEADS*SEQ*4);  // softmax denominators (chunk-local)
  u8*   mTa = mT;
  u8*   mTb = mT + E;

  char* S = ws + off;
  size_t availS = (ws_size > off) ? ws_size - off : 0;
  // S-region temporal plan: [wqkb|qkraw] -> [.|.|w1b|w2b|hbuf|pbuf] -> [attn chunk fp8]
  u16* wqkb  = (u16*)(S);
  u16* qkraw = (u16*)(S + 4194304);
  u16* w1b   = (u16*)(S + 20971520);
  u16* w2b   = (u16*)(S + 29360128);
  u16* hbuf  = (u16*)(S + 37748736);
  u8*  attn  = (u8*)(S);
  u16* xb    = (u16*)mT;                     // alias (2E bytes): dead before k_step0

  const int rcs[6] = {4096, 2048, 1024, 512, 256, 128};
  int RC = 0;
  for (int i = 0; i < 6; i++)
    if (37748736ull + (size_t)rcs[i]*4096*2 <= availS) { RC = rcs[i]; break; }
  const int chs[6] = {32, 16, 8, 4, 2, 1};
  int CH = 0;
  for (int i = 0; i < 6; i++)
    if ((size_t)chs[i]*SEQ*SEQ <= availS) { CH = chs[i]; break; }
  if (RC == 0 || CH == 0) {
    k_zero<<<(out_size+255)/256, 256, 0, stream>>>(out, out_size);
    return;
  }
  // split-K partial buffer (2 x RC x NDIM fp32) after hbuf; fallback if it doesn't fit
  size_t pboff = 37748736ull + (size_t)RC*4096*2;
  int use_ksp = (pboff + (size_t)RC*NDIM*8 <= availS) ? 1 : 0;
  float* pbuf = (float*)(S + pboff);

  const int M = BQ*SEQ;  // 4096

  // dtype probe + canonical bf16 conversion
  k_flag0<<<1, 64, 0, stream>>>(flag);
  k_probe<<<256, 256, 0, stream>>>((const u16*)x, flag);
  k_convert<<<(int)(E/256), 256, 0, stream>>>(x, xb, flag, (int)E);
  k_convert<<<NW_QK/256, 256, 0, stream>>>(w_qk, wqkb, flag, NW_QK);
  k_convert<<<NW1/256, 256, 0, stream>>>(w1, w1b, flag, NW1);
  k_convert<<<NW2/256, 256, 0, stream>>>(w2, w2b, flag, NW2);

  k_norm_scale<<<M, 256, 0, stream>>>(xb, xs);
  { dim3 g(M/128, 2048/128); k_gemm<1,0,0><<<g, 256, 0, stream>>>(xs, wqkb, nullptr, qkraw, nullptr, M, 2048, 1024); }
  k_headnorm<<<M*HEADS, 64, 0, stream>>>(qkraw, qb, kb);

  for (int c = 0; c < M/RC; c++) {
    const u16* xsc = xs + (size_t)c*RC*NDIM;
    { dim3 g(RC/128, 4096/128); k_gemm<1,1,0><<<g, 256, 0, stream>>>(xsc, w1b, nullptr, hbuf, nullptr, RC, 4096, 1024); }
    if (use_ksp) {
      dim3 g(RC/128, 1024/128, 2);
      k_gemm_w2ks<<<g, 512, 0, stream>>>(hbuf, w2b, pbuf, RC, 1024, 4096);
      int n = RC*NDIM;
      k_w2red<<<n/1024, 256, 0, stream>>>(pbuf, pbuf + n, xsc, xf + (size_t)c*RC*NDIM, n);
    } else {
      dim3 g(RC/128, 1024/128);
      k_gemm_w2<<<g, 512, 0, stream>>>(hbuf, w2b, xf + (size_t)c*RC*NDIM, xsc, RC, 1024, 4096);
    }
  }

  // step 0 closed form: m1 = mag(xf + m0v) since normalized attn rows sum to 1 and m0 is constant
  float t0 = 0.5f*(1.0f + sqrtf(1.0f + 64.0f/511.0f));
  float m0v = 1.0f/(2.0f*t0);
  k_step0<<<BQ*HEADS*32, 256, 0, stream>>>(xf, mTa, m0v);

  for (int c0 = 0; c0 < BQ*HEADS; c0 += CH) {
    k_attn<<<CH*32, 256, 0, stream>>>(qb, kb, attn, rsum, c0, CH);
    for (int s = 1; s < NSTEPS; s++) {
      u8* src = (s & 1) ? mTa : mTb;
      u8* dst = (s & 1) ? mTb : mTa;
      if (s == NSTEPS-1)
        k_step<1><<<CH*32, 256, 0, stream>>>(attn, src, xf, rsum, nullptr, out, c0, CH);
      else
        k_step<0><<<CH*32, 256, 0, stream>>>(attn, src, xf, rsum, dst, nullptr, c0, CH);
    }
  }
}

// Round 16
// 495.331 us; speedup vs baseline: 3.5453x; 1.0406x over previous
//
#include <hip/hip_runtime.h>
#include <hip/hip_bf16.h>
#include <math.h>

#define BQ 2
#define SEQ 2048
#define NDIM 1024
#define HEADS 16
#define DH 64
#define NSTEPS 8
#define SCALE 22.60530911f      /* sqrt(511) */
#define SCALE_HEAD 5.567764363f /* sqrt(31)  */
#define INV_SCALE2 (1.0f/511.0f)
#define EXS 8.0325527f          /* SCALE_HEAD * log2(e) */

typedef unsigned short u16;
typedef unsigned char u8;
typedef long long i64;
typedef __attribute__((ext_vector_type(8))) short bf16x8;   // 8 bf16 = 4 VGPR
typedef __attribute__((ext_vector_type(4))) float floatx4;  // MFMA 16x16 acc
typedef __attribute__((ext_vector_type(2))) long long i64x2; // 16B = two fp8 K=32 frags

__device__ __forceinline__ float bf2f(u16 u) {
  union { unsigned int i; float f; } v; v.i = ((unsigned int)u) << 16; return v.f;
}
__device__ __forceinline__ u16 f2bf(float f) {
  union { float f; unsigned int i; } v; v.f = f;
  unsigned int x = v.i;
  return (u16)((x + 0x7fffu + ((x >> 16) & 1u)) >> 16);
}
// raw v_exp_f32 via compiler-modeled builtin (inputs bounded here)
#if __has_builtin(__builtin_amdgcn_exp2f)
__device__ __forceinline__ float exp2_raw(float x) { return __builtin_amdgcn_exp2f(x); }
#else
__device__ __forceinline__ float exp2_raw(float x) { return exp2f(x); }
#endif
#if __has_builtin(__builtin_amdgcn_rcpf)
__device__ __forceinline__ float rcp_raw(float x) { return __builtin_amdgcn_rcpf(x); }
#else
__device__ __forceinline__ float rcp_raw(float x) { return 1.0f/x; }
#endif

// tanh-approx GELU: max |diff vs exact| ~5e-4, below bf16 output quantization.
__device__ __forceinline__ float gelu_tanh(float v) {
  float v2 = v*v;
  float u = v * __builtin_fmaf(0.0356774081f, v2, 0.7978845608f);
  float t = exp2_raw(2.8853900817779268f * u);   // e^{2u}, u in [-5.6, 5.6]
  float th = (t - 1.0f) * rcp_raw(t + 1.0f);
  return 0.5f * v * (1.0f + th);
}

// packed fp8 conversion via HW cvt (gfx950 native fp8 = OCP e4m3fn)
__device__ __forceinline__ int pk4_fp8(float a, float b, float c, float d) {
  int p = 0;
  p = __builtin_amdgcn_cvt_pk_fp8_f32(a, b, p, false);
  p = __builtin_amdgcn_cvt_pk_fp8_f32(c, d, p, true);
  return p;
}

// async global->LDS, 16B per lane; LDS dest = wave-uniform base + lane*16
#define GLD16(gp, lp) __builtin_amdgcn_global_load_lds( \
    (__attribute__((address_space(1))) void*)(gp),      \
    (__attribute__((address_space(3))) void*)(lp), 16, 0, 0)

/* ===================== FRAG-TILED OPERAND LAYOUTS =====================
 * A (attn, per bh_local, 4MB): element e_raw[i][j]:
 *   I=i>>4, kt2=j>>6, hf=(j>>5)&1, Lhi=(j>>3)&3, e=j&7, l15=i&15
 *   addr = ((I*32 + kt2)*64 + Lhi*16 + l15)*16 + hf*8 + e
 * B (m, per bh, 128KB): element m[d][j]:
 *   nt=d>>4, l15=d&15, kt2=j>>6, hf=(j>>5)&1, Lhi=(j>>3)&3, e=j&7
 *   addr = ((nt*32 + kt2)*64 + Lhi*16 + l15)*16 + hf*8 + e
 * Lane L of an MFMA then loads its frag as one dwordx4 at base + L*16. */

// ---------------- dtype probe: flag=1 if input is fp32 ----------------
__global__ void k_flag0(int* flag) { if (threadIdx.x == 0 && blockIdx.x == 0) *flag = 0; }

__global__ __launch_bounds__(256) void k_probe(const u16* __restrict__ x, int* __restrict__ flag) {
  int i = blockIdx.x * 256 + threadIdx.x;
  float v = bf2f(x[i]);
  if (!(fabsf(v) <= 1e4f)) atomicOr(flag, 1);
}

__global__ __launch_bounds__(256) void k_convert(const void* __restrict__ in, u16* __restrict__ outb,
                                                 const int* __restrict__ flag, int n) {
  int i = blockIdx.x * 256 + threadIdx.x;
  if (i >= n) return;
  if (*flag) outb[i] = f2bf(((const float*)in)[i]);
  else       outb[i] = ((const u16*)in)[i];
}

// ---------------- FUSED convert + normalize + scale x -> xs (bf16) ----------------
// Reads raw input (fp32 or bf16 per flag) directly: kills the x-convert pass
// (8.4MB write + 8.4MB re-read) and one launch.
__global__ __launch_bounds__(256) void k_norm_scale_f(const void* __restrict__ xin,
                                                      const int* __restrict__ flag,
                                                      u16* __restrict__ xs) {
  __shared__ float red[256];
  int row = blockIdx.x;
  u16* orow = xs + (size_t)row * NDIM;
  int t = threadIdx.x;
  float vals[4]; float s = 0.f;
  if (*flag) {
    const float* xr = (const float*)xin + (size_t)row * NDIM;
#pragma unroll
    for (int e = 0; e < 4; e++) { float v = xr[t + 256*e]; vals[e] = v; s += v*v; }
  } else {
    const u16* xr = (const u16*)xin + (size_t)row * NDIM;
#pragma unroll
    for (int e = 0; e < 4; e++) { float v = bf2f(xr[t + 256*e]); vals[e] = v; s += v*v; }
  }
  red[t] = s; __syncthreads();
  for (int o = 128; o > 0; o >>= 1) { if (t < o) red[t] += red[t+o]; __syncthreads(); }
  float sc = SCALE / fmaxf(sqrtf(red[0]), 1e-12f);
#pragma unroll
  for (int e = 0; e < 4; e++) orow[t + 256*e] = f2bf(vals[e] * sc);
}

// ---------------- MFMA GEMM (bf16), BK=64 via dual 32-col slabs ----------------
template<int OUT_BF16, int GELU, int ADDSRC>
__global__ __launch_bounds__(256) void k_gemm(const u16* __restrict__ A, const u16* __restrict__ W,
                                              float* __restrict__ Cf, u16* __restrict__ Cb,
                                              const u16* __restrict__ addsrc, int M, int N, int K) {
  __shared__ __align__(16) u16 As[2][128*32];
  __shared__ __align__(16) u16 Bs[2][128*32];
  int t = threadIdx.x;
  int w = t >> 6, L = t & 63;
  int quad = L >> 4, l15 = L & 15;
  int wr = w >> 1, wc = w & 1;
  int bm = blockIdx.x * 128, bn = blockIdx.y * 128;
  int srow = L >> 2, scol = (L & 3) * 8;
  floatx4 acc[4][4];
#pragma unroll
  for (int i = 0; i < 4; i++)
#pragma unroll
    for (int j = 0; j < 4; j++) acc[i][j] = (floatx4){0.f,0.f,0.f,0.f};

  for (int k0 = 0; k0 < K; k0 += 64) {
#pragma unroll
    for (int c = 0; c < 2; c++) {
      int r = c*64 + w*16 + srow;
      const u16* ap = A + (size_t)(bm + r)*K + k0 + scol;
      const u16* wp = W + (size_t)(bn + r)*K + k0 + scol;
      GLD16(ap,      &As[0][(c*64 + w*16)*32]);
      GLD16(ap + 32, &As[1][(c*64 + w*16)*32]);
      GLD16(wp,      &Bs[0][(c*64 + w*16)*32]);
      GLD16(wp + 32, &Bs[1][(c*64 + w*16)*32]);
    }
    __syncthreads();
#pragma unroll
    for (int s = 0; s < 2; s++) {
      bf16x8 af[4], bfr[4];
#pragma unroll
      for (int mt = 0; mt < 4; mt++) af[mt]  = *(const bf16x8*)&As[s][(wr*64 + mt*16 + l15)*32 + quad*8];
#pragma unroll
      for (int nt = 0; nt < 4; nt++) bfr[nt] = *(const bf16x8*)&Bs[s][(wc*64 + nt*16 + l15)*32 + quad*8];
#pragma unroll
      for (int mt = 0; mt < 4; mt++)
#pragma unroll
        for (int nt = 0; nt < 4; nt++)
          acc[mt][nt] = __builtin_amdgcn_mfma_f32_16x16x32_bf16(af[mt], bfr[nt], acc[mt][nt], 0, 0, 0);
    }
    __syncthreads();
  }
#pragma unroll
  for (int mt = 0; mt < 4; mt++)
#pragma unroll
    for (int reg = 0; reg < 4; reg++) {
      int m = bm + wr*64 + mt*16 + quad*4 + reg;
      size_t rowoff = (size_t)m * N;
#pragma unroll
      for (int nt = 0; nt < 4; nt++) {
        int n = bn + wc*64 + nt*16 + l15;
        float v = acc[mt][nt][reg];
        if (GELU) v = gelu_tanh(v);
        if (ADDSRC) v += bf2f(addsrc[rowoff + n]);
        if (OUT_BF16) Cb[rowoff + n] = f2bf(v);
        else Cf[rowoff + n] = v;
      }
    }
}

// ---------------- w2 GEMM fallback: intra-block split-K only (1 block/CU) ----------
__global__ __launch_bounds__(512) void k_gemm_w2(const u16* __restrict__ A, const u16* __restrict__ W,
                                                 float* __restrict__ Cf,
                                                 const u16* __restrict__ addsrc, int M, int N, int K) {
  __shared__ __align__(16) u16 As[2][128*32];
  __shared__ __align__(16) u16 Bs[2][128*32];
  int t = threadIdx.x;
  int g = t >> 8;
  int tg = t & 255;
  int w = tg >> 6;
  int L = t & 63;
  int quad = L >> 4, l15 = L & 15;
  int wr = w >> 1, wc = w & 1;
  int bm = blockIdx.x * 128, bn = blockIdx.y * 128;
  int srow = L >> 2, scol = (L & 3) * 8;
  int kg0 = g * (K >> 1);
  floatx4 acc[4][4];
#pragma unroll
  for (int i = 0; i < 4; i++)
#pragma unroll
    for (int j = 0; j < 4; j++) acc[i][j] = (floatx4){0.f,0.f,0.f,0.f};

  for (int k0 = 0; k0 < (K >> 1); k0 += 32) {
    int kk = kg0 + k0;
#pragma unroll
    for (int c = 0; c < 2; c++) {
      int r = c*64 + w*16 + srow;
      GLD16(A + (size_t)(bm + r)*K + kk + scol, &As[g][(c*64 + w*16)*32]);
      GLD16(W + (size_t)(bn + r)*K + kk + scol, &Bs[g][(c*64 + w*16)*32]);
    }
    __syncthreads();
    bf16x8 af[4], bfr[4];
#pragma unroll
    for (int mt = 0; mt < 4; mt++) af[mt]  = *(const bf16x8*)&As[g][(wr*64 + mt*16 + l15)*32 + quad*8];
#pragma unroll
    for (int nt = 0; nt < 4; nt++) bfr[nt] = *(const bf16x8*)&Bs[g][(wc*64 + nt*16 + l15)*32 + quad*8];
#pragma unroll
    for (int mt = 0; mt < 4; mt++)
#pragma unroll
      for (int nt = 0; nt < 4; nt++)
        acc[mt][nt] = __builtin_amdgcn_mfma_f32_16x16x32_bf16(af[mt], bfr[nt], acc[mt][nt], 0, 0, 0);
    __syncthreads();
  }
  float* LFA = (float*)&As[0][0];
  float* LFB = (float*)&Bs[0][0];
#pragma unroll
  for (int r = 0; r < 2; r++) {
    float* myW = g ? LFA : LFB;
    int mtW = g ? r : (2 + r);
#pragma unroll
    for (int reg = 0; reg < 4; reg++)
#pragma unroll
      for (int nt = 0; nt < 4; nt++)
        myW[(wr*16 + quad*4 + reg)*128 + wc*64 + nt*16 + l15] = acc[mtW][nt][reg];
    __syncthreads();
    float* myR = g ? LFB : LFA;
    int mtS = g ? (2 + r) : r;
#pragma unroll
    for (int reg = 0; reg < 4; reg++) {
      int m = bm + wr*64 + mtS*16 + quad*4 + reg;
      size_t rowoff = (size_t)m * N;
#pragma unroll
      for (int nt = 0; nt < 4; nt++) {
        int n = bn + wc*64 + nt*16 + l15;
        float v = acc[mtS][nt][reg] + myR[(wr*16 + quad*4 + reg)*128 + wc*64 + nt*16 + l15];
        v += bf2f(addsrc[rowoff + n]);
        Cf[rowoff + n] = v;
      }
    }
    __syncthreads();
  }
}

// ---------------- w2 GEMM: inter-block (z=2) + intra-block (g=2) split-K, BK=64 ------
// Same structure as R12's proven kernel, but each K-quarter group now runs BK=64
// via dual 32-col slabs (LDS 32->64KB, still 2 blocks/CU at 512 thr): barrier-pair
// count halves 32->16 with 32 MFMA per drain (the R10->R11 w1 lever, +18% there).
__global__ __launch_bounds__(512) void k_gemm_w2ks(const u16* __restrict__ A, const u16* __restrict__ W,
                                                   float* __restrict__ pbuf, int M, int N, int K) {
  __shared__ __align__(16) u16 As[2][2][128*32];
  __shared__ __align__(16) u16 Bs[2][2][128*32];
  int t = threadIdx.x;
  int g = t >> 8;                 // K-quarter group within block (wave-uniform)
  int tg = t & 255;
  int w = tg >> 6;
  int L = t & 63;
  int quad = L >> 4, l15 = L & 15;
  int wr = w >> 1, wc = w & 1;
  int bm = blockIdx.x * 128, bn = blockIdx.y * 128;
  int z = blockIdx.z;             // K-half
  int srow = L >> 2, scol = (L & 3) * 8;
  int kg0 = z * (K >> 1) + g * (K >> 2);
  floatx4 acc[4][4];
#pragma unroll
  for (int i = 0; i < 4; i++)
#pragma unroll
    for (int j = 0; j < 4; j++) acc[i][j] = (floatx4){0.f,0.f,0.f,0.f};

  for (int k0 = 0; k0 < (K >> 2); k0 += 64) {
    int kk = kg0 + k0;
#pragma unroll
    for (int c = 0; c < 2; c++) {
      int r = c*64 + w*16 + srow;
      const u16* ap = A + (size_t)(bm + r)*K + kk + scol;
      const u16* wp = W + (size_t)(bn + r)*K + kk + scol;
      GLD16(ap,      &As[g][0][(c*64 + w*16)*32]);
      GLD16(ap + 32, &As[g][1][(c*64 + w*16)*32]);
      GLD16(wp,      &Bs[g][0][(c*64 + w*16)*32]);
      GLD16(wp + 32, &Bs[g][1][(c*64 + w*16)*32]);
    }
    __syncthreads();
#pragma unroll
    for (int s = 0; s < 2; s++) {
      bf16x8 af[4], bfr[4];
#pragma unroll
      for (int mt = 0; mt < 4; mt++) af[mt]  = *(const bf16x8*)&As[g][s][(wr*64 + mt*16 + l15)*32 + quad*8];
#pragma unroll
      for (int nt = 0; nt < 4; nt++) bfr[nt] = *(const bf16x8*)&Bs[g][s][(wc*64 + nt*16 + l15)*32 + quad*8];
#pragma unroll
      for (int mt = 0; mt < 4; mt++)
#pragma unroll
        for (int nt = 0; nt < 4; nt++)
          acc[mt][nt] = __builtin_amdgcn_mfma_f32_16x16x32_bf16(af[mt], bfr[nt], acc[mt][nt], 0, 0, 0);
    }
    __syncthreads();
  }
  float* LFA = (float*)&As[0][0][0];
  float* LFB = (float*)&Bs[0][0][0];
  float* pb = pbuf + (size_t)z * M * N;
#pragma unroll
  for (int r = 0; r < 2; r++) {
    float* myW = g ? LFA : LFB;
    int mtW = g ? r : (2 + r);
#pragma unroll
    for (int reg = 0; reg < 4; reg++)
#pragma unroll
      for (int nt = 0; nt < 4; nt++)
        myW[(wr*16 + quad*4 + reg)*128 + wc*64 + nt*16 + l15] = acc[mtW][nt][reg];
    __syncthreads();
    float* myR = g ? LFB : LFA;
    int mtS = g ? (2 + r) : r;
#pragma unroll
    for (int reg = 0; reg < 4; reg++) {
      int m = bm + wr*64 + mtS*16 + quad*4 + reg;
      size_t rowoff = (size_t)m * N;
#pragma unroll
      for (int nt = 0; nt < 4; nt++) {
        int n = bn + wc*64 + nt*16 + l15;
        pb[rowoff + n] = acc[mtS][nt][reg] + myR[(wr*16 + quad*4 + reg)*128 + wc*64 + nt*16 + l15];
      }
    }
    __syncthreads();
  }
}

// reduce: xf = p0 + p1 + bf16(xs); vectorized x4
__global__ __launch_bounds__(256) void k_w2red(const float* __restrict__ p0, const float* __restrict__ p1,
                                               const u16* __restrict__ xs, float* __restrict__ xf, int n) {
  int i = (blockIdx.x * 256 + threadIdx.x) * 4;
  if (i >= n) return;
  float4 a = *(const float4*)(p0 + i);
  float4 b = *(const float4*)(p1 + i);
  ushort4 s = *(const ushort4*)(xs + i);
  float4 o;
  o.x = a.x + b.x + bf2f(s.x);
  o.y = a.y + b.y + bf2f(s.y);
  o.z = a.z + b.z + bf2f(s.z);
  o.w = a.w + b.w + bf2f(s.w);
  *(float4*)(xf + i) = o;
}

// ---------------- per-head normalize q,k -> [B,H,N,DH] bf16 ----------------
__global__ __launch_bounds__(64) void k_headnorm(const u16* __restrict__ qkraw,
                                                 u16* __restrict__ qn, u16* __restrict__ kn) {
  int blk = blockIdx.x;
  int h = blk & (HEADS-1); int bi = blk >> 4;
  int b = bi >> 11, i = bi & (SEQ-1);
  int d = threadIdx.x;
  const u16* base = qkraw + (size_t)bi * (2*NDIM);
  float qv = bf2f(base[h*DH + d]);
  float kv = bf2f(base[NDIM + h*DH + d]);
  float qs = qv*qv, ks = kv*kv;
#pragma unroll
  for (int o = 32; o > 0; o >>= 1) { qs += __shfl_xor(qs, o); ks += __shfl_xor(ks, o); }
  size_t oidx = ((size_t)(b*HEADS + h) * SEQ + i) * DH + d;
  qn[oidx] = f2bf(qv / fmaxf(sqrtf(qs), 1e-12f));
  kn[oidx] = f2bf(kv / fmaxf(sqrtf(ks), 1e-12f));
}

// ---------------- MFMA attn: 64 i-rows per wave + XCD affinity + T5 setprio ----------
__global__ __launch_bounds__(256, 4) void k_attn(const u16* __restrict__ qb, const u16* __restrict__ kb,
                                                 u8* __restrict__ attn, float* __restrict__ rowsum,
                                                 int bh0, int CH) {
  __shared__ __align__(16) u8 buf[4][4][64][16];   // [wave][i-subtile][row][16B]
  __shared__ float reds[4][4][16];                 // [wave][i-subtile][l15]
  int t = threadIdx.x;
  int w = t >> 6, L = t & 63;
  int quad = L >> 4, l15 = L & 15;
  int blk = blockIdx.x;
  int bh_local, islice;
  if (CH >= 8) {
    int gpb = CH >> 3;                             // bh-groups per XCD
    int q = blk >> 3;
    bh_local = (blk & 7) + 8 * (q % gpb);          // blk%8 == bh_local%8 == XCD
    islice = q / gpb;                              // [0,32)
  } else {
    bh_local = blk >> 5;
    islice = blk & 31;
  }
  int bh = bh0 + bh_local;
  int i0blk = islice * 64;
  bf16x8 q0[4], q1[4];
#pragma unroll
  for (int s = 0; s < 4; s++) {
    const u16* qrow = qb + ((size_t)bh*SEQ + i0blk + s*16 + l15)*DH + quad*8;
    q0[s] = *(const bf16x8*)qrow;
    q1[s] = *(const bf16x8*)(qrow + 32);
  }
  const u16* kbase = kb + (size_t)bh*SEQ*DH;
  u8* abase = attn + ((size_t)bh_local << 22) + (size_t)(i0blk >> 4)*32768;
  float sa[4] = {0.f, 0.f, 0.f, 0.f};
  for (int g = 0; g < 8; g++) {
#pragma unroll 2
    for (int tt4 = 0; tt4 < 4; tt4++) {
      int j = w*512 + (g*4 + tt4)*16 + l15;
      const u16* krow = kbase + (size_t)j*DH + quad*8;
      bf16x8 a0 = *(const bf16x8*)krow;
      bf16x8 a1 = *(const bf16x8*)(krow + 32);
      int dl = ((tt4*2 + (quad>>1)) & 3)*16 + l15;
      int boff = (tt4>>1)*8 + (quad&1)*4;
      floatx4 cs[4];
      __builtin_amdgcn_s_setprio(1);
#pragma unroll
      for (int s = 0; s < 4; s++) {
        floatx4 c = (floatx4){0.f,0.f,0.f,0.f};
        c = __builtin_amdgcn_mfma_f32_16x16x32_bf16(a0, q0[s], c, 0, 0, 0);
        cs[s] = __builtin_amdgcn_mfma_f32_16x16x32_bf16(a1, q1[s], c, 0, 0, 0);
      }
      __builtin_amdgcn_s_setprio(0);
#pragma unroll
      for (int s = 0; s < 4; s++) {
        float e0 = exp2_raw(EXS * cs[s][0]);
        float e1 = exp2_raw(EXS * cs[s][1]);
        float e2 = exp2_raw(EXS * cs[s][2]);
        float e3 = exp2_raw(EXS * cs[s][3]);
        sa[s] += (e0 + e1) + (e2 + e3);          // all for the same i
        *(int*)&buf[w][s][dl][boff] = pk4_fp8(e0, e1, e2, e3);
      }
    }
#pragma unroll
    for (int s = 0; s < 4; s++) {
      uint4 v = *(const uint4*)&buf[w][s][L][0];
      *(uint4*)(abase + (size_t)s*32768 + (size_t)(w*8 + g)*1024 + (size_t)L*16) = v;
    }
  }
#pragma unroll
  for (int s = 0; s < 4; s++) {
    float v = sa[s];
    v += __shfl_xor(v, 16); v += __shfl_xor(v, 32);
    if (quad == 0) reds[w][s][l15] = v;
  }
  __syncthreads();
  if (t < 64)
    rowsum[(size_t)bh_local*SEQ + i0blk + t] =
        (reds[0][t >> 4][t & 15] + reds[1][t >> 4][t & 15]) +
        (reds[2][t >> 4][t & 15] + reds[3][t >> 4][t & 15]);
}

__global__ void k_zero(float* __restrict__ o, int n) {
  int i = blockIdx.x*256 + threadIdx.x; if (i < n) o[i] = 0.f;
}

// ---------------- step-0 shortcut: m1 = mag(xf + m0v) -> frag-tiled fp8 ----------------
__global__ __launch_bounds__(256) void k_step0(const float* __restrict__ xf, u8* __restrict__ mT,
                                               float m0v) {
  __shared__ __align__(16) u8 tile_t[64][72];   // [d][i_local], +8 pad
  int bh = blockIdx.x >> 5;       // 32 i-tiles per bh
  int kt2 = blockIdx.x & 31;
  int i0 = kt2 * 64;
  int b = bh >> 4, h = bh & (HEADS-1);
  int t = threadIdx.x;
  int row = t >> 2, part = t & 3;            // i-row in tile, 16-float d-part
  const float* xr = xf + ((size_t)b*SEQ + i0 + row)*NDIM + h*DH + part*16;
  float v[16]; float s = 0.f;
#pragma unroll
  for (int e = 0; e < 16; e++) { float u = xr[e] + m0v; v[e] = u; s += u*u; }
  s += __shfl_xor(s, 1); s += __shfl_xor(s, 2);
  float t2 = 0.5f*(1.0f + sqrtf(1.0f + s * INV_SCALE2));
  float inv = 1.0f/(2.0f*t2);
#pragma unroll
  for (int e = 0; e < 16; e += 4) {
    int p = pk4_fp8(v[e]*inv, v[e+1]*inv, v[e+2]*inv, v[e+3]*inv);
    tile_t[part*16 + e + 0][row] = (u8)(p & 255);
    tile_t[part*16 + e + 1][row] = (u8)((p >> 8) & 255);
    tile_t[part*16 + e + 2][row] = (u8)((p >> 16) & 255);
    tile_t[part*16 + e + 3][row] = (u8)((p >> 24) & 255);
  }
  __syncthreads();
  int nt = t >> 6, Lw = t & 63;
  i64 lo = *(const i64*)&tile_t[nt*16 + (Lw & 15)][(Lw >> 4)*8];
  i64 hi = *(const i64*)&tile_t[nt*16 + (Lw & 15)][32 + (Lw >> 4)*8];
  u8* dst = mT + ((size_t)bh << 17) + ((size_t)(nt*32 + kt2)*64 + Lw)*16;
  *(i64*)dst = lo;
  *(i64*)(dst + 8) = hi;
}

// ---------------- fp8 MFMA mean-field step: NO LDS + XCD affinity + T5 setprio ----
template<int LAST>
__global__ __launch_bounds__(256) void k_step(const u8* __restrict__ attn, const u8* __restrict__ mT_in,
                                              const float* __restrict__ xf,
                                              const float* __restrict__ rowsum,
                                              u8* __restrict__ mT_out,
                                              float* __restrict__ out, int bh0, int CH) {
  int t = threadIdx.x;
  int w = t >> 6, L = t & 63;
  int quad = L >> 4, l15 = L & 15;
  int blk = blockIdx.x;
  int bh_local, I4;
  if (CH >= 8) {
    int gpb = CH >> 3;               // bh-groups per XCD
    int q = blk >> 3;
    bh_local = (blk & 7) + 8 * (q % gpb);   // blk%8 == bh_local%8 == XCD
    I4 = q / gpb;
  } else {
    bh_local = blk >> 5;
    I4 = blk & 31;
  }
  int bh = bh0 + bh_local;
  int I = I4*4 + w;                  // i-tile [0,128)
  int b = bh >> 4, hh = bh & (HEADS-1);
  const u8* ab = attn + ((size_t)bh_local << 22) + (size_t)I*32768 + (size_t)L*16;
  const u8* bb = mT_in + ((size_t)bh << 17) + (size_t)L*16;
  floatx4 acc[4];
#pragma unroll
  for (int j = 0; j < 4; j++) acc[j] = (floatx4){0.f,0.f,0.f,0.f};

#pragma unroll 4
  for (int kt2 = 0; kt2 < 32; kt2++) {
    i64x2 a  = *(const i64x2*)(ab + (size_t)kt2*1024);
    i64x2 b0 = *(const i64x2*)(bb + (size_t)kt2*1024);
    i64x2 b1 = *(const i64x2*)(bb + (size_t)(32 + kt2)*1024);
    i64x2 b2 = *(const i64x2*)(bb + (size_t)(64 + kt2)*1024);
    i64x2 b3 = *(const i64x2*)(bb + (size_t)(96 + kt2)*1024);
    __builtin_amdgcn_s_setprio(1);
    acc[0] = __builtin_amdgcn_mfma_f32_16x16x32_fp8_fp8(a.x, b0.x, acc[0], 0, 0, 0);
    acc[1] = __builtin_amdgcn_mfma_f32_16x16x32_fp8_fp8(a.x, b1.x, acc[1], 0, 0, 0);
    acc[2] = __builtin_amdgcn_mfma_f32_16x16x32_fp8_fp8(a.x, b2.x, acc[2], 0, 0, 0);
    acc[3] = __builtin_amdgcn_mfma_f32_16x16x32_fp8_fp8(a.x, b3.x, acc[3], 0, 0, 0);
    acc[0] = __builtin_amdgcn_mfma_f32_16x16x32_fp8_fp8(a.y, b0.y, acc[0], 0, 0, 0);
    acc[1] = __builtin_amdgcn_mfma_f32_16x16x32_fp8_fp8(a.y, b1.y, acc[1], 0, 0, 0);
    acc[2] = __builtin_amdgcn_mfma_f32_16x16x32_fp8_fp8(a.y, b2.y, acc[2], 0, 0, 0);
    acc[3] = __builtin_amdgcn_mfma_f32_16x16x32_fp8_fp8(a.y, b3.y, acc[3], 0, 0, 0);
    __builtin_amdgcn_s_setprio(0);
  }
  int ibase = I*16 + quad*4;
  float th[4][4]; float invr[4];
#pragma unroll
  for (int reg = 0; reg < 4; reg++) {
    float sinv = 1.0f / rowsum[(size_t)bh_local*SEQ + ibase + reg];
    size_t xoff = ((size_t)b*SEQ + ibase + reg)*NDIM + hh*DH + l15;
    float s = 0.f;
#pragma unroll
    for (int nt = 0; nt < 4; nt++) {
      float v = acc[nt][reg]*sinv + xf[xoff + nt*16];
      th[nt][reg] = v; s += v*v;
    }
    s += __shfl_xor(s, 1); s += __shfl_xor(s, 2); s += __shfl_xor(s, 4); s += __shfl_xor(s, 8);
    float tt2 = 0.5f*(1.0f + sqrtf(1.0f + s * INV_SCALE2));
    invr[reg] = 1.0f/(2.0f*tt2);
  }
  if (LAST) {
#pragma unroll
    for (int reg = 0; reg < 4; reg++) {
      size_t ooff = ((size_t)b*SEQ + ibase + reg)*NDIM + hh*DH + l15;
#pragma unroll
      for (int nt = 0; nt < 4; nt++) out[ooff + nt*16] = th[nt][reg]*invr[reg];
    }
  } else {
    int kt2o = I >> 2;
    int hf = (I >> 1) & 1;
    int lhi = ((I & 1)*2 + (quad >> 1)) & 3;
    u8* ob = mT_out + ((size_t)bh << 17) + (size_t)(lhi*16 + l15)*16 + hf*8 + (quad & 1)*4;
#pragma unroll
    for (int nt = 0; nt < 4; nt++) {
      int p = pk4_fp8(th[nt][0]*invr[0], th[nt][1]*invr[1],
                      th[nt][2]*invr[2], th[nt][3]*invr[3]);
      *(int*)(ob + (size_t)(nt*32 + kt2o)*1024) = p;
    }
  }
}

extern "C" void kernel_launch(void* const* d_in, const int* in_sizes, int n_in,
                              void* d_out, int out_size, void* d_ws, size_t ws_size,
                              hipStream_t stream) {
  const void* x    = d_in[0];
  const void* w_qk = d_in[1];
  const void* w1   = d_in[2];
  const void* w2   = d_in[3];
  float* out = (float*)d_out;

  const size_t E = (size_t)BQ*SEQ*NDIM;     // 4,194,304
  const int NW_QK = 2*NDIM*NDIM;
  const int NW1   = 4*NDIM*NDIM;
  const int NW2   = 4*NDIM*NDIM;

  char* ws = (char*)d_ws;
  size_t off = 0;
  auto alloc = [&](size_t bytes) { void* p = ws + off; off += (bytes + 255) & ~255ull; return p; };
  int*  flag = (int*)alloc(256);
  u16*  xs  = (u16*)alloc(E*2);             // scaled-normalized x (bf16)
  u16*  qb  = (u16*)alloc(E*2);             // q normalized [B,H,N,DH] bf16
  u16*  kb  = (u16*)alloc(E*2);
  float* xf = (float*)alloc(E*4);           // external field fp32
  u8*   mT  = (u8*)alloc(E*2);              // two fp8 m-buffers, frag-tiled
  float* rsum = (float*)alloc((size_t)BQ*HEADS*SEQ*4);  // softmax denominators (chunk-local)
  u8*   mTa = mT;
  u8*   mTb = mT + E;

  char* S = ws + off;
  size_t availS = (ws_size > off) ? ws_size - off : 0;
  // S-region temporal plan: [wqkb|qkraw] -> [.|.|w1b|w2b|hbuf|pbuf] -> [attn chunk fp8]
  u16* wqkb  = (u16*)(S);
  u16* qkraw = (u16*)(S + 4194304);
  u16* w1b   = (u16*)(S + 20971520);
  u16* w2b   = (u16*)(S + 29360128);
  u16* hbuf  = (u16*)(S + 37748736);
  u8*  attn  = (u8*)(S);

  const int rcs[6] = {4096, 2048, 1024, 512, 256, 128};
  int RC = 0;
  for (int i = 0; i < 6; i++)
    if (37748736ull + (size_t)rcs[i]*4096*2 <= availS) { RC = rcs[i]; break; }
  const int chs[6] = {32, 16, 8, 4, 2, 1};
  int CH = 0;
  for (int i = 0; i < 6; i++)
    if ((size_t)chs[i]*SEQ*SEQ <= availS) { CH = chs[i]; break; }
  if (RC == 0 || CH == 0) {
    k_zero<<<(out_size+255)/256, 256, 0, stream>>>(out, out_size);
    return;
  }
  // split-K partial buffer (2 x RC x NDIM fp32) after hbuf; fallback if it doesn't fit
  size_t pboff = 37748736ull + (size_t)RC*4096*2;
  int use_ksp = (pboff + (size_t)RC*NDIM*8 <= availS) ? 1 : 0;
  float* pbuf = (float*)(S + pboff);

  const int M = BQ*SEQ;  // 4096

  // dtype probe + canonical bf16 conversion (weights only; x fused into norm_scale)
  k_flag0<<<1, 64, 0, stream>>>(flag);
  k_probe<<<256, 256, 0, stream>>>((const u16*)x, flag);
  k_convert<<<NW_QK/256, 256, 0, stream>>>(w_qk, wqkb, flag, NW_QK);
  k_convert<<<NW1/256, 256, 0, stream>>>(w1, w1b, flag, NW1);
  k_convert<<<NW2/256, 256, 0, stream>>>(w2, w2b, flag, NW2);

  k_norm_scale_f<<<M, 256, 0, stream>>>(x, flag, xs);
  { dim3 g(M/128, 2048/128); k_gemm<1,0,0><<<g, 256, 0, stream>>>(xs, wqkb, nullptr, qkraw, nullptr, M, 2048, 1024); }
  k_headnorm<<<M*HEADS, 64, 0, stream>>>(qkraw, qb, kb);

  for (int c = 0; c < M/RC; c++) {
    const u16* xsc = xs + (size_t)c*RC*NDIM;
    { dim3 g(RC/128, 4096/128); k_gemm<1,1,0><<<g, 256, 0, stream>>>(xsc, w1b, nullptr, hbuf, nullptr, RC, 4096, 1024); }
    if (use_ksp) {
      dim3 g(RC/128, 1024/128, 2);
      k_gemm_w2ks<<<g, 512, 0, stream>>>(hbuf, w2b, pbuf, RC, 1024, 4096);
      int n = RC*NDIM;
      k_w2red<<<n/1024, 256, 0, stream>>>(pbuf, pbuf + n, xsc, xf + (size_t)c*RC*NDIM, n);
    } else {
      dim3 g(RC/128, 1024/128);
      k_gemm_w2<<<g, 512, 0, stream>>>(hbuf, w2b, xf + (size_t)c*RC*NDIM, xsc, RC, 1024, 4096);
    }
  }

  // step 0 closed form: m1 = mag(xf + m0v) since normalized attn rows sum to 1 and m0 is constant
  float t0 = 0.5f*(1.0f + sqrtf(1.0f + 64.0f/511.0f));
  float m0v = 1.0f/(2.0f*t0);
  k_step0<<<BQ*HEADS*32, 256, 0, stream>>>(xf, mTa, m0v);

  for (int c0 = 0; c0 < BQ*HEADS; c0 += CH) {
    k_attn<<<CH*32, 256, 0, stream>>>(qb, kb, attn, rsum, c0, CH);
    for (int s = 1; s < NSTEPS; s++) {
      u8* src = (s & 1) ? mTa : mTb;
      u8* dst = (s & 1) ? mTb : mTa;
      if (s == NSTEPS-1)
        k_step<1><<<CH*32, 256, 0, stream>>>(attn, src, xf, rsum, nullptr, out, c0, CH);
      else
        k_step<0><<<CH*32, 256, 0, stream>>>(attn, src, xf, rsum, dst, nullptr, c0, CH);
    }
  }
}